// Round 1
// baseline (1375.985 us; speedup 1.0000x reference)
//
#include <hip/hip_runtime.h>
#include <math.h>

// Dims (fixed by setup_inputs): B=4, N=2048, C1=64, C2=128, P=1024, Q=16, L=64, V=64, OUT=40
// BN = B*N = 8192, QP = Q*P = 16384
#define BN_EPS 1e-5f

// ---------------------------------------------------------------- conv1 (bias dropped: cancels in BN)
__global__ void k_conv1(const float* __restrict__ x, const float* __restrict__ w1,
                        float* __restrict__ y1) {
    int bn = blockIdx.x * 256 + threadIdx.x;      // 0..8191
    int o  = blockIdx.y;                           // 0..63
    int b = bn >> 11, n = bn & 2047;
    const float* xb = x + (size_t)b * 6144 + n;    // x[b][c][n], c stride 2048
    y1[o * 8192 + bn] = w1[o*3+0]*xb[0] + w1[o*3+1]*xb[2048] + w1[o*3+2]*xb[4096];
}

// ---------------------------------------------------------------- per-channel batch stats over 8192 elems
__global__ void k_stats(const float* __restrict__ y, float* __restrict__ mean,
                        float* __restrict__ inv) {
    int c = blockIdx.x, t = threadIdx.x;
    float s = 0.f, ss = 0.f;
    for (int i = t; i < 8192; i += 256) { float v = y[c*8192 + i]; s += v; ss = fmaf(v, v, ss); }
    __shared__ float rs[256], rss[256];
    rs[t] = s; rss[t] = ss;
    __syncthreads();
    for (int off = 128; off > 0; off >>= 1) {
        if (t < off) { rs[t] += rs[t+off]; rss[t] += rss[t+off]; }
        __syncthreads();
    }
    if (t == 0) {
        float m = rs[0] * (1.f/8192.f);
        float var = rss[0] * (1.f/8192.f) - m*m;
        mean[c] = m;
        inv[c]  = rsqrtf(var + BN_EPS);
    }
}

// ---------------------------------------------------------------- BN + ReLU (elementwise, in-place ok)
__global__ void k_bnrelu(const float* __restrict__ y, float* __restrict__ h,
                         const float* __restrict__ mean, const float* __restrict__ inv,
                         const float* __restrict__ g, const float* __restrict__ be, int total) {
    int i = blockIdx.x * 256 + threadIdx.x;
    if (i >= total) return;
    int c = i >> 13;                               // / 8192
    float v = (y[i] - mean[c]) * inv[c] * g[c] + be[c];
    h[i] = v > 0.f ? v : 0.f;
}

// ---------------------------------------------------------------- conv2: y2[o][bn] = sum_c w2[o][c] h1[c][bn]
__global__ __launch_bounds__(256) void k_conv2(const float* __restrict__ h1,
                                               const float* __restrict__ w2,
                                               float* __restrict__ y2) {
    int bn  = blockIdx.x * 256 + threadIdx.x;
    int og0 = blockIdx.y * 8;
    float acc[8];
#pragma unroll
    for (int j = 0; j < 8; ++j) acc[j] = 0.f;
    for (int c = 0; c < 64; ++c) {
        float hv = h1[c*8192 + bn];
#pragma unroll
        for (int j = 0; j < 8; ++j) acc[j] = fmaf(w2[(og0+j)*64 + c], hv, acc[j]);
    }
#pragma unroll
    for (int j = 0; j < 8; ++j) y2[(og0+j)*8192 + bn] = acc[j];
}

// ---------------------------------------------------------------- THE BIG ONE
// u[qp][bn] = w3[qp][:] . h2[:][bn]  (K=128), fused reductions over bn:
//   per (qp,b): max, min over n ; per qp: sum, sumsq over all 8192 bn.
// Block: 64 qp rows, loops over all 128 bn-chunks of 64. Grid = 256 blocks.
__global__ __launch_bounds__(256) void k_caps(const float* __restrict__ w3,
                                              const float* __restrict__ h2,
                                              float* __restrict__ umax, float* __restrict__ umin,
                                              float* __restrict__ usum, float* __restrict__ usumsq) {
    __shared__ float As[128][68];   // k-major transposed w3 tile: As[k][row]
    __shared__ float Bs[128][64];   // Bs[k][col]
    const int t = threadIdx.x;
    const int qp0 = blockIdx.x * 64;

    // load 64x128 w3 tile (coalesced float4), store transposed
#pragma unroll
    for (int it = 0; it < 8; ++it) {
        int flat = it * 1024 + t * 4;
        int row = flat >> 7, col = flat & 127;
        float4 d = *reinterpret_cast<const float4*>(w3 + (size_t)(qp0 + row) * 128 + col);
        As[col  ][row] = d.x; As[col+1][row] = d.y; As[col+2][row] = d.z; As[col+3][row] = d.w;
    }

    const int ty = t >> 4, tx = t & 15;
    const int row0 = ty * 4, col0 = tx * 4;
    float maxv[4][4], minv[4][4], sum[4], sumsq[4];
#pragma unroll
    for (int i = 0; i < 4; ++i) {
        sum[i] = 0.f; sumsq[i] = 0.f;
#pragma unroll
        for (int bi = 0; bi < 4; ++bi) { maxv[i][bi] = -__builtin_inff(); minv[i][bi] = __builtin_inff(); }
    }

#pragma unroll
    for (int bi = 0; bi < 4; ++bi) {            // batch index (compile-time for reg arrays)
        for (int ch2 = 0; ch2 < 32; ++ch2) {    // 32 chunks of 64 columns within this b
            const int bn0 = bi * 2048 + ch2 * 64;
            __syncthreads();
#pragma unroll
            for (int it = 0; it < 8; ++it) {
                int flat = it * 1024 + t * 4;
                int c = flat >> 6, j = flat & 63;
                *reinterpret_cast<float4*>(&Bs[c][j]) =
                    *reinterpret_cast<const float4*>(h2 + (size_t)c * 8192 + bn0 + j);
            }
            __syncthreads();
            float acc[4][4];
#pragma unroll
            for (int i = 0; i < 4; ++i)
#pragma unroll
                for (int j = 0; j < 4; ++j) acc[i][j] = 0.f;
#pragma unroll 8
            for (int k = 0; k < 128; ++k) {
                float4 a  = *reinterpret_cast<const float4*>(&As[k][row0]);
                float4 bv = *reinterpret_cast<const float4*>(&Bs[k][col0]);
                float av[4]  = {a.x, a.y, a.z, a.w};
                float bvv[4] = {bv.x, bv.y, bv.z, bv.w};
#pragma unroll
                for (int i = 0; i < 4; ++i)
#pragma unroll
                    for (int j = 0; j < 4; ++j) acc[i][j] = fmaf(av[i], bvv[j], acc[i][j]);
            }
#pragma unroll
            for (int i = 0; i < 4; ++i)
#pragma unroll
                for (int j = 0; j < 4; ++j) {
                    float v = acc[i][j];
                    maxv[i][bi] = fmaxf(maxv[i][bi], v);
                    minv[i][bi] = fminf(minv[i][bi], v);
                    sum[i] += v;
                    sumsq[i] = fmaf(v, v, sumsq[i]);
                }
        }
    }

    // reduce across the 16 tx lanes (contiguous lanes within a wave)
#pragma unroll
    for (int off = 8; off >= 1; off >>= 1) {
#pragma unroll
        for (int i = 0; i < 4; ++i) {
#pragma unroll
            for (int bi = 0; bi < 4; ++bi) {
                maxv[i][bi] = fmaxf(maxv[i][bi], __shfl_xor(maxv[i][bi], off));
                minv[i][bi] = fminf(minv[i][bi], __shfl_xor(minv[i][bi], off));
            }
            sum[i]   += __shfl_xor(sum[i], off);
            sumsq[i] += __shfl_xor(sumsq[i], off);
        }
    }
    if (tx == 0) {
#pragma unroll
        for (int i = 0; i < 4; ++i) {
            int r = qp0 + row0 + i;
#pragma unroll
            for (int bi = 0; bi < 4; ++bi) { umax[bi*16384 + r] = maxv[i][bi]; umin[bi*16384 + r] = minv[i][bi]; }
            usum[r] = sum[i]; usumsq[r] = sumsq[i];
        }
    }
}

// ---------------------------------------------------------------- BN3 (analytic, sign-safe) + squash over Q
__global__ void k_u(const float* __restrict__ umax, const float* __restrict__ umin,
                    const float* __restrict__ usum, const float* __restrict__ usumsq,
                    const float* __restrict__ g3, const float* __restrict__ be3,
                    float* __restrict__ u) {
    int tg = blockIdx.x * 256 + threadIdx.x;       // 0..4095 : (b,p)
    int b = tg >> 10, p = tg & 1023;
    float ub[16]; float sn = 0.f;
#pragma unroll
    for (int q = 0; q < 16; ++q) {
        int qp = q * 1024 + p;
        float mean  = usum[qp] * (1.f/8192.f);
        float var   = usumsq[qp] * (1.f/8192.f) - mean*mean;
        float scale = g3[qp] * rsqrtf(var + BN_EPS);
        float val = (scale >= 0.f) ? umax[b*16384 + qp] : umin[b*16384 + qp];   // bn monotone in sign(scale)
        float vb = (val - mean) * scale + be3[qp];
        ub[q] = vb; sn = fmaf(vb, vb, sn);
    }
    float f = sqrtf(sn) / (1.f + sn);              // squash factor
#pragma unroll
    for (int q = 0; q < 16; ++q) u[tg*16 + q] = ub[q] * f;
}

// ---------------------------------------------------------------- u_hat[b][l][p][v] = sum_q Wr[l][p][v][q] u[b][p][q]
__global__ __launch_bounds__(256) void k_uhat(const float* __restrict__ Wr,
                                              const float* __restrict__ u,
                                              float* __restrict__ uhat) {
    const int p = blockIdx.x, l = blockIdx.y;
    const int t = threadIdx.x;
    __shared__ float wr[16][64];                   // [q][v], conflict-free reads
    __shared__ float us[4][16];
    const float* src = Wr + (size_t)(l * 1024 + p) * 1024;
    float4 d = *reinterpret_cast<const float4*>(src + 4 * t);
    int vv = t >> 2, q0 = (t & 3) * 4;
    wr[q0  ][vv] = d.x; wr[q0+1][vv] = d.y; wr[q0+2][vv] = d.z; wr[q0+3][vv] = d.w;
    if (t < 64) us[t >> 4][t & 15] = u[((t >> 4) * 1024 + p) * 16 + (t & 15)];
    __syncthreads();
    int b = t >> 6, v = t & 63;
    float acc = 0.f;
#pragma unroll
    for (int q = 0; q < 16; ++q) acc = fmaf(wr[q][v], us[b][q], acc);
    uhat[((size_t)(b * 64 + l) * 1024 + p) * 64 + v] = acc;
}

// ---------------------------------------------------------------- pass A: s1 = (1/64) sum_p u_hat
__global__ void k_passA(const float* __restrict__ uhat, float* __restrict__ s1) {
    const int t = threadIdx.x, v = t & 63, pi = t >> 6;
    const float* base = uhat + (size_t)blockIdx.x * 65536;   // (b*64+l)*P*V
    float acc = 0.f;
    for (int p = pi; p < 1024; p += 4) acc += base[p * 64 + v];
    __shared__ float red[4][64];
    red[pi][v] = acc;
    __syncthreads();
    if (t < 64) s1[blockIdx.x * 64 + t] = (red[0][t] + red[1][t] + red[2][t] + red[3][t]) * (1.f/64.f);
}

// ---------------------------------------------------------------- squash over V (one wave per (b,l))
__global__ void k_squash64(const float* __restrict__ s, float* __restrict__ vout) {
    const int wv = blockIdx.x, lane = threadIdx.x;
    float xv = s[wv * 64 + lane];
    float sn = xv * xv;
#pragma unroll
    for (int off = 32; off >= 1; off >>= 1) sn += __shfl_xor(sn, off);
    vout[wv * 64 + lane] = xv * sqrtf(sn) / (1.f + sn);
}

// ---------------------------------------------------------------- routing pass (B or C):
// per p: b_new[l] = (read_b ? bij : 0) + v_in[b][l][:].u_hat[b][l][p][:] ; c = softmax_l(b_new);
// accumulate s += c[l]*u_hat. Grid: 4 b x 64 chunks of 16 p. Partials reduced later.
__global__ __launch_bounds__(256) void k_route(const float* __restrict__ uhat,
                                               const float* __restrict__ vin,
                                               float* __restrict__ bij,
                                               float* __restrict__ part, const int read_b) {
    const int blk = blockIdx.x;
    const int b = blk >> 6, ch = blk & 63;
    const int p0 = ch * 16;
    const int t = threadIdx.x;
    const int v = t & 63, w = t >> 6;
    __shared__ float uh[64][64];
    __shared__ float vs[64][64];
    __shared__ float bl[64];
    __shared__ float cl[64];
    for (int i = t; i < 4096; i += 256) vs[i >> 6][i & 63] = vin[b * 4096 + i];
    float sacc[16];
#pragma unroll
    for (int j = 0; j < 16; ++j) sacc[j] = 0.f;

    for (int pp = 0; pp < 16; ++pp) {
        const int p = p0 + pp;
        __syncthreads();
        const float* src = uhat + (size_t)b * 4194304 + (size_t)p * 64;   // b*L*P*V
        for (int i = t; i < 4096; i += 256) {
            int l = i >> 6;
            uh[l][i & 63] = src[(size_t)l * 65536 + (i & 63)];
        }
        __syncthreads();
#pragma unroll
        for (int i = 0; i < 16; ++i) {
            const int l = w * 16 + i;
            float prod = uh[l][v] * vs[l][v];
#pragma unroll
            for (int off = 32; off >= 1; off >>= 1) prod += __shfl_xor(prod, off);
            if (v == 0) {
                float bb = prod;
                if (read_b) bb += bij[(b * 64 + l) * 1024 + p];
                bl[l] = bb;
                if (!read_b) bij[(b * 64 + l) * 1024 + p] = bb;
            }
        }
        __syncthreads();
        if (w == 0) {                               // softmax over l (lane = l)
            float xv = bl[v];
            float m = xv;
#pragma unroll
            for (int off = 32; off >= 1; off >>= 1) m = fmaxf(m, __shfl_xor(m, off));
            float e = expf(xv - m);
            float sgm = e;
#pragma unroll
            for (int off = 32; off >= 1; off >>= 1) sgm += __shfl_xor(sgm, off);
            cl[v] = e / sgm;
        }
        __syncthreads();
#pragma unroll
        for (int j = 0; j < 16; ++j) {
            const int l = j * 4 + w;
            sacc[j] = fmaf(cl[l], uh[l][v], sacc[j]);
        }
    }
#pragma unroll
    for (int j = 0; j < 16; ++j) {
        const int l = j * 4 + w;
        part[((size_t)(b * 64 + ch) * 64 + l) * 64 + v] = sacc[j];
    }
}

// ---------------------------------------------------------------- reduce partials + squash (+ presence)
__global__ void k_red_squash(const float* __restrict__ part, float* __restrict__ vout,
                             float* __restrict__ pres) {
    const int wv = blockIdx.x;                      // b*64 + l
    const int b = wv >> 6, l = wv & 63;
    const int v = threadIdx.x;
    float acc = 0.f;
    for (int ch = 0; ch < 64; ++ch) acc += part[((size_t)(b * 64 + ch) * 64 + l) * 64 + v];
    float sn = acc * acc;
#pragma unroll
    for (int off = 32; off >= 1; off >>= 1) sn += __shfl_xor(sn, off);
    vout[wv * 64 + v] = acc * sqrtf(sn) / (1.f + sn);
    if (pres != nullptr && v == 0) pres[wv] = sn / (1.f + sn);   // ||squash(s)|| = sn/(1+sn)
}

// ---------------------------------------------------------------- classifier head
__global__ void k_logits(const float* __restrict__ vj, const float* __restrict__ fcw,
                         const float* __restrict__ fcb, float* __restrict__ out) {
    int wv = blockIdx.x * 4 + (threadIdx.x >> 6);   // 0..159
    int lane = threadIdx.x & 63;
    int b = wv / 40, o = wv % 40;
    const float* xv = vj + b * 4096;
    const float* wr = fcw + (size_t)o * 4096;
    float acc = 0.f;
    for (int i = lane; i < 4096; i += 64) acc = fmaf(xv[i], wr[i], acc);
#pragma unroll
    for (int off = 32; off >= 1; off >>= 1) acc += __shfl_xor(acc, off);
    if (lane == 0) out[b * 40 + o] = acc + fcb[o];
}

extern "C" void kernel_launch(void* const* d_in, const int* in_sizes, int n_in,
                              void* d_out, int out_size, void* d_ws, size_t ws_size,
                              hipStream_t stream) {
    const float* x   = (const float*)d_in[0];
    const float* w1  = (const float*)d_in[1];
    // d_in[2] = b1: cancels under batch-norm
    const float* g1  = (const float*)d_in[3];
    const float* be1 = (const float*)d_in[4];
    const float* w2  = (const float*)d_in[5];
    // d_in[6] = b2: cancels
    const float* g2  = (const float*)d_in[7];
    const float* be2 = (const float*)d_in[8];
    const float* w3  = (const float*)d_in[9];
    // d_in[10] = b3: cancels
    const float* g3  = (const float*)d_in[11];
    const float* be3 = (const float*)d_in[12];
    const float* Wr  = (const float*)d_in[13];
    const float* fcw = (const float*)d_in[14];
    const float* fcb = (const float*)d_in[15];
    float* out = (float*)d_out;

    float* ws     = (float*)d_ws;
    float* y1     = ws;                   // [64][8192]   (BN/ReLU in place)
    float* y2     = y1 + 524288;          // [128][8192]
    float* mean1  = y2 + 1048576;         // 64
    float* inv1   = mean1 + 64;           // 64
    float* mean2  = inv1 + 64;            // 128
    float* inv2   = mean2 + 128;          // 128
    float* umax   = inv2 + 128;           // [4][16384]
    float* umin   = umax + 65536;         // [4][16384]
    float* usum   = umin + 65536;         // [16384]
    float* usumsq = usum + 16384;         // [16384]
    float* u      = usumsq + 16384;       // [4][1024][16]
    float* s1     = u + 65536;            // [4][64][64]
    float* v1     = s1 + 16384;
    float* v2     = v1 + 16384;
    float* vj     = v2 + 16384;
    float* bij    = vj + 16384;           // [4][64][1024]
    float* part   = bij + 262144;         // [4][64][64][64]
    float* uhat   = part + 1048576;       // [4][64][1024][64]  (64 MB)

    k_conv1<<<dim3(32, 64), 256, 0, stream>>>(x, w1, y1);
    k_stats<<<64, 256, 0, stream>>>(y1, mean1, inv1);
    k_bnrelu<<<2048, 256, 0, stream>>>(y1, y1, mean1, inv1, g1, be1, 524288);
    k_conv2<<<dim3(32, 16), 256, 0, stream>>>(y1, w2, y2);
    k_stats<<<128, 256, 0, stream>>>(y2, mean2, inv2);
    k_bnrelu<<<4096, 256, 0, stream>>>(y2, y2, mean2, inv2, g2, be2, 1048576);
    k_caps<<<256, 256, 0, stream>>>(w3, y2, umax, umin, usum, usumsq);
    k_u<<<16, 256, 0, stream>>>(umax, umin, usum, usumsq, g3, be3, u);
    k_uhat<<<dim3(1024, 64), 256, 0, stream>>>(Wr, u, uhat);
    k_passA<<<256, 256, 0, stream>>>(uhat, s1);
    k_squash64<<<256, 64, 0, stream>>>(s1, v1);
    k_route<<<256, 256, 0, stream>>>(uhat, v1, bij, part, 0);
    k_red_squash<<<256, 64, 0, stream>>>(part, v2, nullptr);
    k_route<<<256, 256, 0, stream>>>(uhat, v2, bij, part, 1);
    k_red_squash<<<256, 64, 0, stream>>>(part, vj, out + 160);
    k_logits<<<40, 256, 0, stream>>>(vj, fcw, fcb, out);
}

// Round 2
// 1060.408 us; speedup vs baseline: 1.2976x; 1.2976x over previous
//
#include <hip/hip_runtime.h>
#include <math.h>

// Dims (fixed by setup_inputs): B=4, N=2048, C1=64, C2=128, P=1024, Q=16, L=64, V=64, OUT=40
// BN = B*N = 8192, QP = Q*P = 16384
#define BN_EPS 1e-5f

typedef __attribute__((ext_vector_type(8))) _Float16 half8;
typedef __attribute__((ext_vector_type(4))) float f32x4;
#define SPLIT_S  2048.0f
#define INV_S    (1.0f/2048.0f)

// ---------------------------------------------------------------- conv1 (bias dropped: cancels in BN)
__global__ void k_conv1(const float* __restrict__ x, const float* __restrict__ w1,
                        float* __restrict__ y1) {
    int bn = blockIdx.x * 256 + threadIdx.x;      // 0..8191
    int o  = blockIdx.y;                           // 0..63
    int b = bn >> 11, n = bn & 2047;
    const float* xb = x + (size_t)b * 6144 + n;    // x[b][c][n], c stride 2048
    y1[o * 8192 + bn] = w1[o*3+0]*xb[0] + w1[o*3+1]*xb[2048] + w1[o*3+2]*xb[4096];
}

// ---------------------------------------------------------------- per-channel batch stats over 8192 elems
__global__ void k_stats(const float* __restrict__ y, float* __restrict__ mean,
                        float* __restrict__ inv) {
    int c = blockIdx.x, t = threadIdx.x;
    float s = 0.f, ss = 0.f;
    for (int i = t; i < 8192; i += 256) { float v = y[c*8192 + i]; s += v; ss = fmaf(v, v, ss); }
    __shared__ float rs[256], rss[256];
    rs[t] = s; rss[t] = ss;
    __syncthreads();
    for (int off = 128; off > 0; off >>= 1) {
        if (t < off) { rs[t] += rs[t+off]; rss[t] += rss[t+off]; }
        __syncthreads();
    }
    if (t == 0) {
        float m = rs[0] * (1.f/8192.f);
        float var = rss[0] * (1.f/8192.f) - m*m;
        mean[c] = m;
        inv[c]  = rsqrtf(var + BN_EPS);
    }
}

// ---------------------------------------------------------------- BN + ReLU (elementwise, in-place ok)
__global__ void k_bnrelu(const float* __restrict__ y, float* __restrict__ h,
                         const float* __restrict__ mean, const float* __restrict__ inv,
                         const float* __restrict__ g, const float* __restrict__ be, int total) {
    int i = blockIdx.x * 256 + threadIdx.x;
    if (i >= total) return;
    int c = i >> 13;                               // / 8192
    float v = (y[i] - mean[c]) * inv[c] * g[c] + be[c];
    h[i] = v > 0.f ? v : 0.f;
}

// ---------------------------------------------------------------- conv2: y2[o][bn] = sum_c w2[o][c] h1[c][bn]
__global__ __launch_bounds__(256) void k_conv2(const float* __restrict__ h1,
                                               const float* __restrict__ w2,
                                               float* __restrict__ y2) {
    int bn  = blockIdx.x * 256 + threadIdx.x;
    int og0 = blockIdx.y * 8;
    float acc[8];
#pragma unroll
    for (int j = 0; j < 8; ++j) acc[j] = 0.f;
    for (int c = 0; c < 64; ++c) {
        float hv = h1[c*8192 + bn];
#pragma unroll
        for (int j = 0; j < 8; ++j) acc[j] = fmaf(w2[(og0+j)*64 + c], hv, acc[j]);
    }
#pragma unroll
    for (int j = 0; j < 8; ++j) y2[(og0+j)*8192 + bn] = acc[j];
}

// ---------------------------------------------------------------- split w3 fp32 -> fp16 hi + scaled lo
__global__ void k_split_w3(const float* __restrict__ w, _Float16* __restrict__ hi,
                           _Float16* __restrict__ lo) {
    int i = (blockIdx.x * 256 + threadIdx.x) * 4;  // total 2097152, multiple of 1024
    float4 d = *reinterpret_cast<const float4*>(w + i);
    float vs[4] = {d.x, d.y, d.z, d.w};
#pragma unroll
    for (int j = 0; j < 4; ++j) {
        _Float16 h = (_Float16)vs[j];
        hi[i + j] = h;
        lo[i + j] = (_Float16)((vs[j] - (float)h) * SPLIT_S);
    }
}

// ---------------------------------------------------------------- BN2+ReLU fused with transpose+split:
// h2t[bn][c] (hi/lo fp16) from y2[c][bn] fp32. 64x64 LDS tile transpose.
__global__ __launch_bounds__(256) void k_h2t_split(const float* __restrict__ y2,
        const float* __restrict__ mean, const float* __restrict__ inv,
        const float* __restrict__ g, const float* __restrict__ be,
        _Float16* __restrict__ hi, _Float16* __restrict__ lo) {
    __shared__ float tile[64][65];
    const int t = threadIdx.x;
    const int bn0 = blockIdx.x * 64, c0 = blockIdx.y * 64;
#pragma unroll
    for (int r = 0; r < 16; ++r) {
        int idx = r * 256 + t;
        int cl = idx >> 6, bnl = idx & 63;          // c wave-uniform -> scalar stat loads
        int c = c0 + cl;
        float v = y2[(size_t)c * 8192 + bn0 + bnl];
        v = (v - mean[c]) * inv[c] * g[c] + be[c];
        tile[cl][bnl] = v > 0.f ? v : 0.f;
    }
    __syncthreads();
#pragma unroll
    for (int r = 0; r < 16; ++r) {
        int idx = r * 256 + t;
        int bnl = idx >> 6, cl = idx & 63;
        float v = tile[cl][bnl];
        _Float16 h = (_Float16)v;
        size_t o = (size_t)(bn0 + bnl) * 128 + c0 + cl;
        hi[o] = h;
        lo[o] = (_Float16)((v - (float)h) * SPLIT_S);
    }
}

// ---------------------------------------------------------------- THE BIG ONE, now on matrix cores.
// u[qp][bn] = w3[qp][:] . h2[:][bn], K=128, via fp16x3 split MFMA (fp32-class accuracy).
// A = w3 [qp][k] row-major, B = h2t [bn][k] row-major (both k-contiguous: direct 16B frag loads).
// Wave: 2 m-tiles (32 rows), A frags preloaded in regs. Block: 4 waves = 128 rows.
// Grid (128 m-blocks, 4 b): per-b max/min complete in block; sum/sumsq per-b partials.
__global__ __launch_bounds__(256) void k_caps(
        const _Float16* __restrict__ w3h, const _Float16* __restrict__ w3l,
        const _Float16* __restrict__ h2h, const _Float16* __restrict__ h2l,
        float* __restrict__ umax, float* __restrict__ umin,
        float* __restrict__ usum_b, float* __restrict__ usumsq_b) {
    const int lane = threadIdx.x & 63, wave = threadIdx.x >> 6;
    const int b = blockIdx.y;
    const int mrow = blockIdx.x * 128 + wave * 32;
    const int r16 = lane & 15, kq = lane >> 4;     // A/B frag: row=lane&15, k=kq*8+j

    half8 Ah[2][4], Al[2][4];
#pragma unroll
    for (int mt = 0; mt < 2; ++mt) {
        const size_t base = (size_t)(mrow + mt*16 + r16) * 128 + kq * 8;
#pragma unroll
        for (int ks = 0; ks < 4; ++ks) {
            Ah[mt][ks] = *reinterpret_cast<const half8*>(w3h + base + ks*32);
            Al[mt][ks] = *reinterpret_cast<const half8*>(w3l + base + ks*32);
        }
    }
    float mx[2][4], mn[2][4], sm[2][4], sq[2][4];
#pragma unroll
    for (int mt = 0; mt < 2; ++mt)
#pragma unroll
        for (int r = 0; r < 4; ++r) {
            mx[mt][r] = -3.4e38f; mn[mt][r] = 3.4e38f; sm[mt][r] = 0.f; sq[mt][r] = 0.f;
        }

    const size_t bbase = (size_t)(b * 2048 + r16) * 128 + kq * 8;
    for (int nt = 0; nt < 128; ++nt) {             // 16 bn-cols per tile
        const size_t nb = bbase + (size_t)nt * 16 * 128;
        f32x4 acc[2], accx[2];
#pragma unroll
        for (int mt = 0; mt < 2; ++mt) { acc[mt] = f32x4{0.f,0.f,0.f,0.f}; accx[mt] = f32x4{0.f,0.f,0.f,0.f}; }
#pragma unroll
        for (int ks = 0; ks < 4; ++ks) {
            half8 Bh = *reinterpret_cast<const half8*>(h2h + nb + ks*32);
            half8 Bl = *reinterpret_cast<const half8*>(h2l + nb + ks*32);
#pragma unroll
            for (int mt = 0; mt < 2; ++mt) {
                acc[mt]  = __builtin_amdgcn_mfma_f32_16x16x32_f16(Ah[mt][ks], Bh, acc[mt], 0, 0, 0);
                accx[mt] = __builtin_amdgcn_mfma_f32_16x16x32_f16(Ah[mt][ks], Bl, accx[mt], 0, 0, 0);
                accx[mt] = __builtin_amdgcn_mfma_f32_16x16x32_f16(Al[mt][ks], Bh, accx[mt], 0, 0, 0);
            }
        }
#pragma unroll
        for (int mt = 0; mt < 2; ++mt)
#pragma unroll
            for (int r = 0; r < 4; ++r) {
                float v = fmaf(accx[mt][r], INV_S, acc[mt][r]);   // u element (fp32-class)
                mx[mt][r] = fmaxf(mx[mt][r], v);
                mn[mt][r] = fminf(mn[mt][r], v);
                sm[mt][r] += v;
                sq[mt][r] = fmaf(v, v, sq[mt][r]);
            }
    }
    // reduce over the 16 column lanes (C/D: col=lane&15, row=kq*4+reg)
#pragma unroll
    for (int off = 8; off >= 1; off >>= 1)
#pragma unroll
        for (int mt = 0; mt < 2; ++mt)
#pragma unroll
            for (int r = 0; r < 4; ++r) {
                mx[mt][r] = fmaxf(mx[mt][r], __shfl_xor(mx[mt][r], off));
                mn[mt][r] = fminf(mn[mt][r], __shfl_xor(mn[mt][r], off));
                sm[mt][r] += __shfl_xor(sm[mt][r], off);
                sq[mt][r] += __shfl_xor(sq[mt][r], off);
            }
    if (r16 == 0) {
#pragma unroll
        for (int mt = 0; mt < 2; ++mt)
#pragma unroll
            for (int r = 0; r < 4; ++r) {
                int qp = mrow + mt*16 + kq*4 + r;
                umax[b*16384 + qp]     = mx[mt][r];
                umin[b*16384 + qp]     = mn[mt][r];
                usum_b[b*16384 + qp]   = sm[mt][r];
                usumsq_b[b*16384 + qp] = sq[mt][r];
            }
    }
}

// ---------------------------------------------------------------- BN3 (analytic, sign-safe) + squash over Q
__global__ void k_u(const float* __restrict__ umax, const float* __restrict__ umin,
                    const float* __restrict__ usum_b, const float* __restrict__ usumsq_b,
                    const float* __restrict__ g3, const float* __restrict__ be3,
                    float* __restrict__ u) {
    int tg = blockIdx.x * 256 + threadIdx.x;       // 0..4095 : (b,p)
    int b = tg >> 10, p = tg & 1023;
    float ub[16]; float sn = 0.f;
#pragma unroll
    for (int q = 0; q < 16; ++q) {
        int qp = q * 1024 + p;
        float s  = usum_b[qp] + usum_b[16384+qp] + usum_b[32768+qp] + usum_b[49152+qp];
        float ss = usumsq_b[qp] + usumsq_b[16384+qp] + usumsq_b[32768+qp] + usumsq_b[49152+qp];
        float mean  = s * (1.f/8192.f);
        float var   = ss * (1.f/8192.f) - mean*mean;
        float scale = g3[qp] * rsqrtf(var + BN_EPS);
        float val = (scale >= 0.f) ? umax[b*16384 + qp] : umin[b*16384 + qp];   // bn monotone in sign(scale)
        float vb = (val - mean) * scale + be3[qp];
        ub[q] = vb; sn = fmaf(vb, vb, sn);
    }
    float f = sqrtf(sn) / (1.f + sn);              // squash factor
#pragma unroll
    for (int q = 0; q < 16; ++q) u[tg*16 + q] = ub[q] * f;
}

// ---------------------------------------------------------------- u_hat[b][l][p][v] = sum_q Wr[l][p][v][q] u[b][p][q]
__global__ __launch_bounds__(256) void k_uhat(const float* __restrict__ Wr,
                                              const float* __restrict__ u,
                                              float* __restrict__ uhat) {
    const int p = blockIdx.x, l = blockIdx.y;
    const int t = threadIdx.x;
    __shared__ float wr[16][64];                   // [q][v], conflict-free reads
    __shared__ float us[4][16];
    const float* src = Wr + (size_t)(l * 1024 + p) * 1024;
    float4 d = *reinterpret_cast<const float4*>(src + 4 * t);
    int vv = t >> 2, q0 = (t & 3) * 4;
    wr[q0  ][vv] = d.x; wr[q0+1][vv] = d.y; wr[q0+2][vv] = d.z; wr[q0+3][vv] = d.w;
    if (t < 64) us[t >> 4][t & 15] = u[((t >> 4) * 1024 + p) * 16 + (t & 15)];
    __syncthreads();
    int b = t >> 6, v = t & 63;
    float acc = 0.f;
#pragma unroll
    for (int q = 0; q < 16; ++q) acc = fmaf(wr[q][v], us[b][q], acc);
    uhat[((size_t)(b * 64 + l) * 1024 + p) * 64 + v] = acc;
}

// ---------------------------------------------------------------- pass A: s1 = (1/64) sum_p u_hat
__global__ void k_passA(const float* __restrict__ uhat, float* __restrict__ s1) {
    const int t = threadIdx.x, v = t & 63, pi = t >> 6;
    const float* base = uhat + (size_t)blockIdx.x * 65536;   // (b*64+l)*P*V
    float acc = 0.f;
    for (int p = pi; p < 1024; p += 4) acc += base[p * 64 + v];
    __shared__ float red[4][64];
    red[pi][v] = acc;
    __syncthreads();
    if (t < 64) s1[blockIdx.x * 64 + t] = (red[0][t] + red[1][t] + red[2][t] + red[3][t]) * (1.f/64.f);
}

// ---------------------------------------------------------------- squash over V (one wave per (b,l))
__global__ void k_squash64(const float* __restrict__ s, float* __restrict__ vout) {
    const int wv = blockIdx.x, lane = threadIdx.x;
    float xv = s[wv * 64 + lane];
    float sn = xv * xv;
#pragma unroll
    for (int off = 32; off >= 1; off >>= 1) sn += __shfl_xor(sn, off);
    vout[wv * 64 + lane] = xv * sqrtf(sn) / (1.f + sn);
}

// ---------------------------------------------------------------- routing pass (B or C):
// per p: b_new[l] = (read_b ? bij : 0) + v_in[b][l][:].u_hat[b][l][p][:] ; c = softmax_l(b_new);
// accumulate s += c[l]*u_hat. Grid: 4 b x 64 chunks of 16 p. Partials reduced later.
__global__ __launch_bounds__(256) void k_route(const float* __restrict__ uhat,
                                               const float* __restrict__ vin,
                                               float* __restrict__ bij,
                                               float* __restrict__ part, const int read_b) {
    const int blk = blockIdx.x;
    const int b = blk >> 6, ch = blk & 63;
    const int p0 = ch * 16;
    const int t = threadIdx.x;
    const int v = t & 63, w = t >> 6;
    __shared__ float uh[64][64];
    __shared__ float vs[64][64];
    __shared__ float bl[64];
    __shared__ float cl[64];
    for (int i = t; i < 4096; i += 256) vs[i >> 6][i & 63] = vin[b * 4096 + i];
    float sacc[16];
#pragma unroll
    for (int j = 0; j < 16; ++j) sacc[j] = 0.f;

    for (int pp = 0; pp < 16; ++pp) {
        const int p = p0 + pp;
        __syncthreads();
        const float* src = uhat + (size_t)b * 4194304 + (size_t)p * 64;   // b*L*P*V
        for (int i = t; i < 4096; i += 256) {
            int l = i >> 6;
            uh[l][i & 63] = src[(size_t)l * 65536 + (i & 63)];
        }
        __syncthreads();
#pragma unroll
        for (int i = 0; i < 16; ++i) {
            const int l = w * 16 + i;
            float prod = uh[l][v] * vs[l][v];
#pragma unroll
            for (int off = 32; off >= 1; off >>= 1) prod += __shfl_xor(prod, off);
            if (v == 0) {
                float bb = prod;
                if (read_b) bb += bij[(b * 64 + l) * 1024 + p];
                bl[l] = bb;
                if (!read_b) bij[(b * 64 + l) * 1024 + p] = bb;
            }
        }
        __syncthreads();
        if (w == 0) {                               // softmax over l (lane = l)
            float xv = bl[v];
            float m = xv;
#pragma unroll
            for (int off = 32; off >= 1; off >>= 1) m = fmaxf(m, __shfl_xor(m, off));
            float e = expf(xv - m);
            float sgm = e;
#pragma unroll
            for (int off = 32; off >= 1; off >>= 1) sgm += __shfl_xor(sgm, off);
            cl[v] = e / sgm;
        }
        __syncthreads();
#pragma unroll
        for (int j = 0; j < 16; ++j) {
            const int l = j * 4 + w;
            sacc[j] = fmaf(cl[l], uh[l][v], sacc[j]);
        }
    }
#pragma unroll
    for (int j = 0; j < 16; ++j) {
        const int l = j * 4 + w;
        part[((size_t)(b * 64 + ch) * 64 + l) * 64 + v] = sacc[j];
    }
}

// ---------------------------------------------------------------- reduce partials + squash (+ presence)
__global__ void k_red_squash(const float* __restrict__ part, float* __restrict__ vout,
                             float* __restrict__ pres) {
    const int wv = blockIdx.x;                      // b*64 + l
    const int b = wv >> 6, l = wv & 63;
    const int v = threadIdx.x;
    float acc = 0.f;
    for (int ch = 0; ch < 64; ++ch) acc += part[((size_t)(b * 64 + ch) * 64 + l) * 64 + v];
    float sn = acc * acc;
#pragma unroll
    for (int off = 32; off >= 1; off >>= 1) sn += __shfl_xor(sn, off);
    vout[wv * 64 + v] = acc * sqrtf(sn) / (1.f + sn);
    if (pres != nullptr && v == 0) pres[wv] = sn / (1.f + sn);   // ||squash(s)|| = sn/(1+sn)
}

// ---------------------------------------------------------------- classifier head
__global__ void k_logits(const float* __restrict__ vj, const float* __restrict__ fcw,
                         const float* __restrict__ fcb, float* __restrict__ out) {
    int wv = blockIdx.x * 4 + (threadIdx.x >> 6);   // 0..159
    int lane = threadIdx.x & 63;
    int b = wv / 40, o = wv % 40;
    const float* xv = vj + b * 4096;
    const float* wr = fcw + (size_t)o * 4096;
    float acc = 0.f;
    for (int i = lane; i < 4096; i += 64) acc = fmaf(xv[i], wr[i], acc);
#pragma unroll
    for (int off = 32; off >= 1; off >>= 1) acc += __shfl_xor(acc, off);
    if (lane == 0) out[b * 40 + o] = acc + fcb[o];
}

extern "C" void kernel_launch(void* const* d_in, const int* in_sizes, int n_in,
                              void* d_out, int out_size, void* d_ws, size_t ws_size,
                              hipStream_t stream) {
    const float* x   = (const float*)d_in[0];
    const float* w1  = (const float*)d_in[1];
    // d_in[2] = b1: cancels under batch-norm
    const float* g1  = (const float*)d_in[3];
    const float* be1 = (const float*)d_in[4];
    const float* w2  = (const float*)d_in[5];
    // d_in[6] = b2: cancels
    const float* g2  = (const float*)d_in[7];
    const float* be2 = (const float*)d_in[8];
    const float* w3  = (const float*)d_in[9];
    // d_in[10] = b3: cancels
    const float* g3  = (const float*)d_in[11];
    const float* be3 = (const float*)d_in[12];
    const float* Wr  = (const float*)d_in[13];
    const float* fcw = (const float*)d_in[14];
    const float* fcb = (const float*)d_in[15];
    float* out = (float*)d_out;

    float* ws       = (float*)d_ws;
    float* y1       = ws;                   // [64][8192]   (BN/ReLU in place)
    float* y2       = y1 + 524288;          // [128][8192]
    float* mean1    = y2 + 1048576;         // 64
    float* inv1     = mean1 + 64;           // 64
    float* mean2    = inv1 + 64;            // 128
    float* inv2     = mean2 + 128;          // 128
    float* umax     = inv2 + 128;           // [4][16384]
    float* umin     = umax + 65536;         // [4][16384]
    float* usum_b   = umin + 65536;         // [4][16384] per-b partials
    float* usumsq_b = usum_b + 65536;       // [4][16384]
    float* u        = usumsq_b + 65536;     // [4][1024][16]
    float* s1       = u + 65536;            // [4][64][64]
    float* v1       = s1 + 16384;
    float* v2       = v1 + 16384;
    float* vj       = v2 + 16384;
    float* bij      = vj + 16384;           // [4][64][1024]
    float* part     = bij + 262144;         // [4][64][64][64]
    float* uhat     = part + 1048576;       // [4][64][1024][64]  (64 MB)
    // fp16 staging buffers alias the uhat region: dead before k_uhat writes it.
    _Float16* w3h = (_Float16*)uhat;        // [16384][128]
    _Float16* w3l = w3h + 2097152;
    _Float16* h2h = w3l + 2097152;          // [8192][128] (bn-major)
    _Float16* h2l = h2h + 1048576;

    k_conv1<<<dim3(32, 64), 256, 0, stream>>>(x, w1, y1);
    k_stats<<<64, 256, 0, stream>>>(y1, mean1, inv1);
    k_bnrelu<<<2048, 256, 0, stream>>>(y1, y1, mean1, inv1, g1, be1, 524288);
    k_conv2<<<dim3(32, 16), 256, 0, stream>>>(y1, w2, y2);
    k_stats<<<128, 256, 0, stream>>>(y2, mean2, inv2);
    k_split_w3<<<2048, 256, 0, stream>>>(w3, w3h, w3l);
    k_h2t_split<<<dim3(128, 2), 256, 0, stream>>>(y2, mean2, inv2, g2, be2, h2h, h2l);
    k_caps<<<dim3(128, 4), 256, 0, stream>>>(w3h, w3l, h2h, h2l, umax, umin, usum_b, usumsq_b);
    k_u<<<16, 256, 0, stream>>>(umax, umin, usum_b, usumsq_b, g3, be3, u);
    k_uhat<<<dim3(1024, 64), 256, 0, stream>>>(Wr, u, uhat);
    k_passA<<<256, 256, 0, stream>>>(uhat, s1);
    k_squash64<<<256, 64, 0, stream>>>(s1, v1);
    k_route<<<256, 256, 0, stream>>>(uhat, v1, bij, part, 0);
    k_red_squash<<<256, 64, 0, stream>>>(part, v2, nullptr);
    k_route<<<256, 256, 0, stream>>>(uhat, v2, bij, part, 1);
    k_red_squash<<<256, 64, 0, stream>>>(part, vj, out + 160);
    k_logits<<<40, 256, 0, stream>>>(vj, fcw, fcb, out);
}

// Round 3
// 767.826 us; speedup vs baseline: 1.7921x; 1.3811x over previous
//
#include <hip/hip_runtime.h>
#include <math.h>

// Dims (fixed by setup_inputs): B=4, N=2048, C1=64, C2=128, P=1024, Q=16, L=64, V=64, OUT=40
// BN = B*N = 8192, QP = Q*P = 16384
#define BN_EPS 1e-5f

typedef __attribute__((ext_vector_type(8))) _Float16 half8;
typedef __attribute__((ext_vector_type(4))) float f32x4;
#define SPLIT_S  2048.0f
#define INV_S    (1.0f/2048.0f)

// ---------------------------------------------------------------- conv1 (bias dropped: cancels in BN)
__global__ void k_conv1(const float* __restrict__ x, const float* __restrict__ w1,
                        float* __restrict__ y1) {
    int bn = blockIdx.x * 256 + threadIdx.x;      // 0..8191
    int o  = blockIdx.y;                           // 0..63
    int b = bn >> 11, n = bn & 2047;
    const float* xb = x + (size_t)b * 6144 + n;    // x[b][c][n], c stride 2048
    y1[o * 8192 + bn] = w1[o*3+0]*xb[0] + w1[o*3+1]*xb[2048] + w1[o*3+2]*xb[4096];
}

// ---------------------------------------------------------------- per-channel batch stats over 8192 elems
__global__ void k_stats(const float* __restrict__ y, float* __restrict__ mean,
                        float* __restrict__ inv) {
    int c = blockIdx.x, t = threadIdx.x;
    float s = 0.f, ss = 0.f;
    const float4* src = (const float4*)(y + c * 8192);
    for (int i = t; i < 2048; i += 256) {
        float4 v = src[i];
        s += v.x + v.y + v.z + v.w;
        ss = fmaf(v.x, v.x, fmaf(v.y, v.y, fmaf(v.z, v.z, fmaf(v.w, v.w, ss))));
    }
    __shared__ float rs[256], rss[256];
    rs[t] = s; rss[t] = ss;
    __syncthreads();
    for (int off = 128; off > 0; off >>= 1) {
        if (t < off) { rs[t] += rs[t+off]; rss[t] += rss[t+off]; }
        __syncthreads();
    }
    if (t == 0) {
        float m = rs[0] * (1.f/8192.f);
        float var = rss[0] * (1.f/8192.f) - m*m;
        mean[c] = m;
        inv[c]  = rsqrtf(var + BN_EPS);
    }
}

// ---------------------------------------------------------------- BN + ReLU (float4, in-place ok)
__global__ void k_bnrelu(const float* __restrict__ y, float* __restrict__ h,
                         const float* __restrict__ mean, const float* __restrict__ inv,
                         const float* __restrict__ g, const float* __restrict__ be, int total4) {
    int i = blockIdx.x * 256 + threadIdx.x;
    if (i >= total4) return;
    int c = i >> 11;                               // (i*4) / 8192
    float sc = inv[c] * g[c], sh = be[c] - mean[c] * sc;
    float4 v = *(const float4*)(y + i * 4);
    v.x = fmaxf(fmaf(v.x, sc, sh), 0.f);
    v.y = fmaxf(fmaf(v.y, sc, sh), 0.f);
    v.z = fmaxf(fmaf(v.z, sc, sh), 0.f);
    v.w = fmaxf(fmaf(v.w, sc, sh), 0.f);
    *(float4*)(h + i * 4) = v;
}

// ---------------------------------------------------------------- conv2: y2[o][bn] = sum_c w2[o][c] h1[c][bn]
__global__ __launch_bounds__(256) void k_conv2(const float* __restrict__ h1,
                                               const float* __restrict__ w2,
                                               float* __restrict__ y2) {
    int bn0 = (blockIdx.x * 256 + threadIdx.x) * 4;
    int og0 = blockIdx.y * 8;
    float4 acc[8];
#pragma unroll
    for (int j = 0; j < 8; ++j) acc[j] = float4{0.f,0.f,0.f,0.f};
    for (int c = 0; c < 64; ++c) {
        float4 hv = *(const float4*)(h1 + c*8192 + bn0);
#pragma unroll
        for (int j = 0; j < 8; ++j) {
            float w = w2[(og0+j)*64 + c];
            acc[j].x = fmaf(w, hv.x, acc[j].x); acc[j].y = fmaf(w, hv.y, acc[j].y);
            acc[j].z = fmaf(w, hv.z, acc[j].z); acc[j].w = fmaf(w, hv.w, acc[j].w);
        }
    }
#pragma unroll
    for (int j = 0; j < 8; ++j) *(float4*)(y2 + (og0+j)*8192 + bn0) = acc[j];
}

// ---------------------------------------------------------------- split w3 fp32 -> fp16 hi + scaled lo
__global__ void k_split_w3(const float* __restrict__ w, _Float16* __restrict__ hi,
                           _Float16* __restrict__ lo) {
    int i = (blockIdx.x * 256 + threadIdx.x) * 4;  // total 2097152, multiple of 1024
    float4 d = *reinterpret_cast<const float4*>(w + i);
    float vs[4] = {d.x, d.y, d.z, d.w};
#pragma unroll
    for (int j = 0; j < 4; ++j) {
        _Float16 h = (_Float16)vs[j];
        hi[i + j] = h;
        lo[i + j] = (_Float16)((vs[j] - (float)h) * SPLIT_S);
    }
}

// ---------------------------------------------------------------- BN2+ReLU fused with transpose+split:
// h2t[bn][c] (hi/lo fp16) from y2[c][bn] fp32. 64x64 LDS tile transpose.
__global__ __launch_bounds__(256) void k_h2t_split(const float* __restrict__ y2,
        const float* __restrict__ mean, const float* __restrict__ inv,
        const float* __restrict__ g, const float* __restrict__ be,
        _Float16* __restrict__ hi, _Float16* __restrict__ lo) {
    __shared__ float tile[64][65];
    const int t = threadIdx.x;
    const int bn0 = blockIdx.x * 64, c0 = blockIdx.y * 64;
#pragma unroll
    for (int r = 0; r < 16; ++r) {
        int idx = r * 256 + t;
        int cl = idx >> 6, bnl = idx & 63;          // c wave-uniform -> scalar stat loads
        int c = c0 + cl;
        float v = y2[(size_t)c * 8192 + bn0 + bnl];
        v = (v - mean[c]) * inv[c] * g[c] + be[c];
        tile[cl][bnl] = v > 0.f ? v : 0.f;
    }
    __syncthreads();
#pragma unroll
    for (int r = 0; r < 16; ++r) {
        int idx = r * 256 + t;
        int bnl = idx >> 6, cl = idx & 63;
        float v = tile[cl][bnl];
        _Float16 h = (_Float16)v;
        size_t o = (size_t)(bn0 + bnl) * 128 + c0 + cl;
        hi[o] = h;
        lo[o] = (_Float16)((v - (float)h) * SPLIT_S);
    }
}

// ---------------------------------------------------------------- THE BIG ONE v3.
// u[qp][bn] = w3[qp][:].h2[:][bn], K=128, fp16x3 split MFMA.
// Block: 64 rows (4 m-tiles, A hi/lo preloaded in regs), 4 waves SPLIT N
// (wave w owns cols nt = j*4+w) -> B panel read once per block (1 GB total,
// was 4.2 GB). Per-(b,row) max/min/sum/sq finished via 4 KB LDS cross-wave
// combine. Grid (256 m-blocks, 4 b) = 1024 blocks.
__global__ __launch_bounds__(256, 2) void k_caps(
        const _Float16* __restrict__ w3h, const _Float16* __restrict__ w3l,
        const _Float16* __restrict__ h2h, const _Float16* __restrict__ h2l,
        float* __restrict__ umax, float* __restrict__ umin,
        float* __restrict__ usum_b, float* __restrict__ usumsq_b) {
    const int lane = threadIdx.x & 63, wave = threadIdx.x >> 6;
    const int b = blockIdx.y;
    const int mrow = blockIdx.x * 64;
    const int r16 = lane & 15, kq = lane >> 4;     // A/B frag: row=lane&15, k=kq*8+j

    half8 Ah[4][4], Al[4][4];
#pragma unroll
    for (int mt = 0; mt < 4; ++mt) {
        const size_t base = (size_t)(mrow + mt*16 + r16) * 128 + kq * 8;
#pragma unroll
        for (int ks = 0; ks < 4; ++ks) {
            Ah[mt][ks] = *reinterpret_cast<const half8*>(w3h + base + ks*32);
            Al[mt][ks] = *reinterpret_cast<const half8*>(w3l + base + ks*32);
        }
    }
    float mx[4][4], mn[4][4], sm[4][4], sq[4][4];
#pragma unroll
    for (int mt = 0; mt < 4; ++mt)
#pragma unroll
        for (int r = 0; r < 4; ++r) {
            mx[mt][r] = -3.4e38f; mn[mt][r] = 3.4e38f; sm[mt][r] = 0.f; sq[mt][r] = 0.f;
        }

    for (int j = 0; j < 32; ++j) {                 // wave w covers nt = j*4+w
        const int nt = j * 4 + wave;
        const size_t nb = (size_t)(b*2048 + nt*16 + r16) * 128 + kq * 8;
        f32x4 acc[4], accx[4];
#pragma unroll
        for (int mt = 0; mt < 4; ++mt) { acc[mt] = f32x4{0.f,0.f,0.f,0.f}; accx[mt] = f32x4{0.f,0.f,0.f,0.f}; }
#pragma unroll
        for (int ks = 0; ks < 4; ++ks) {
            half8 Bh = *reinterpret_cast<const half8*>(h2h + nb + ks*32);
            half8 Bl = *reinterpret_cast<const half8*>(h2l + nb + ks*32);
#pragma unroll
            for (int mt = 0; mt < 4; ++mt) {
                acc[mt]  = __builtin_amdgcn_mfma_f32_16x16x32_f16(Ah[mt][ks], Bh, acc[mt], 0, 0, 0);
                accx[mt] = __builtin_amdgcn_mfma_f32_16x16x32_f16(Ah[mt][ks], Bl, accx[mt], 0, 0, 0);
                accx[mt] = __builtin_amdgcn_mfma_f32_16x16x32_f16(Al[mt][ks], Bh, accx[mt], 0, 0, 0);
            }
        }
#pragma unroll
        for (int mt = 0; mt < 4; ++mt)
#pragma unroll
            for (int r = 0; r < 4; ++r) {
                float v = fmaf(accx[mt][r], INV_S, acc[mt][r]);   // u element (fp32-class)
                mx[mt][r] = fmaxf(mx[mt][r], v);
                mn[mt][r] = fminf(mn[mt][r], v);
                sm[mt][r] += v;
                sq[mt][r] = fmaf(v, v, sq[mt][r]);
            }
    }
    // reduce over the 16 column lanes (C/D: col=lane&15, row=kq*4+reg)
#pragma unroll
    for (int off = 8; off >= 1; off >>= 1)
#pragma unroll
        for (int mt = 0; mt < 4; ++mt)
#pragma unroll
            for (int r = 0; r < 4; ++r) {
                mx[mt][r] = fmaxf(mx[mt][r], __shfl_xor(mx[mt][r], off));
                mn[mt][r] = fminf(mn[mt][r], __shfl_xor(mn[mt][r], off));
                sm[mt][r] += __shfl_xor(sm[mt][r], off);
                sq[mt][r] += __shfl_xor(sq[mt][r], off);
            }
    // cross-wave combine (waves hold same rows, different n-subsets)
    __shared__ float sred[4][4][64];               // [stat][wave][row]
    if (r16 == 0) {
#pragma unroll
        for (int mt = 0; mt < 4; ++mt)
#pragma unroll
            for (int r = 0; r < 4; ++r) {
                int row = mt*16 + kq*4 + r;
                sred[0][wave][row] = mx[mt][r];
                sred[1][wave][row] = mn[mt][r];
                sred[2][wave][row] = sm[mt][r];
                sred[3][wave][row] = sq[mt][r];
            }
    }
    __syncthreads();
    if (threadIdx.x < 64) {
        const int t = threadIdx.x;
        float M = sred[0][0][t], m = sred[1][0][t], s = sred[2][0][t], q = sred[3][0][t];
#pragma unroll
        for (int w = 1; w < 4; ++w) {
            M = fmaxf(M, sred[0][w][t]);
            m = fminf(m, sred[1][w][t]);
            s += sred[2][w][t];
            q += sred[3][w][t];
        }
        umax[b*16384 + mrow + t]     = M;
        umin[b*16384 + mrow + t]     = m;
        usum_b[b*16384 + mrow + t]   = s;
        usumsq_b[b*16384 + mrow + t] = q;
    }
}

// ---------------------------------------------------------------- BN3 (analytic, sign-safe) + squash over Q
__global__ void k_u(const float* __restrict__ umax, const float* __restrict__ umin,
                    const float* __restrict__ usum_b, const float* __restrict__ usumsq_b,
                    const float* __restrict__ g3, const float* __restrict__ be3,
                    float* __restrict__ u) {
    int tg = blockIdx.x * 256 + threadIdx.x;       // 0..4095 : (b,p)
    int b = tg >> 10, p = tg & 1023;
    float ub[16]; float sn = 0.f;
#pragma unroll
    for (int q = 0; q < 16; ++q) {
        int qp = q * 1024 + p;
        float s  = usum_b[qp] + usum_b[16384+qp] + usum_b[32768+qp] + usum_b[49152+qp];
        float ss = usumsq_b[qp] + usumsq_b[16384+qp] + usumsq_b[32768+qp] + usumsq_b[49152+qp];
        float mean  = s * (1.f/8192.f);
        float var   = ss * (1.f/8192.f) - mean*mean;
        float scale = g3[qp] * rsqrtf(var + BN_EPS);
        float val = (scale >= 0.f) ? umax[b*16384 + qp] : umin[b*16384 + qp];   // bn monotone in sign(scale)
        float vb = (val - mean) * scale + be3[qp];
        ub[q] = vb; sn = fmaf(vb, vb, sn);
    }
    float f = sqrtf(sn) / (1.f + sn);              // squash factor
#pragma unroll
    for (int q = 0; q < 16; ++q) u[tg*16 + q] = ub[q] * f;
}

// ---------------------------------------------------------------- u_hat[b][l][p][v] = sum_q Wr[l][p][v][q] u[b][p][q]
// 4 p per block: 16 KB contiguous Wr read, float4.
__global__ __launch_bounds__(256) void k_uhat(const float* __restrict__ Wr,
                                              const float* __restrict__ u,
                                              float* __restrict__ uhat) {
    const int t = threadIdx.x;
    const int p0 = blockIdx.x * 4, l = blockIdx.y;
    __shared__ float wr[4][16][68];                // [p][q][v] padded
    __shared__ float us[4][4][16];                 // [p][b][q]
    const float* src = Wr + ((size_t)l * 1024 + p0) * 1024;
#pragma unroll
    for (int it = 0; it < 4; ++it) {
        float4 d = *(const float4*)(src + (it*256 + t) * 4);
        int v = t >> 2, q0 = (t & 3) * 4;          // p = it (wave-uniform)
        wr[it][q0  ][v] = d.x; wr[it][q0+1][v] = d.y;
        wr[it][q0+2][v] = d.z; wr[it][q0+3][v] = d.w;
    }
    {
        int p = t >> 6, bb = (t >> 4) & 3, q = t & 15;
        us[p][bb][q] = u[((size_t)bb * 1024 + p0 + p) * 16 + q];
    }
    __syncthreads();
    const int bb = t >> 6, v = t & 63;
#pragma unroll
    for (int p = 0; p < 4; ++p) {
        float acc = 0.f;
#pragma unroll
        for (int q = 0; q < 16; ++q) acc = fmaf(wr[p][q][v], us[p][bb][q], acc);
        uhat[((size_t)(bb * 64 + l) * 1024 + p0 + p) * 64 + v] = acc;
    }
}

// ---------------------------------------------------------------- pass A: s1 = (1/64) sum_p u_hat, squash fused
__global__ void k_passA(const float* __restrict__ uhat, float* __restrict__ vout) {
    const int t = threadIdx.x;
    const int c4 = t & 15, pr = t >> 4;            // v0 = c4*4, p = pr + 16*it
    const float* base = uhat + (size_t)blockIdx.x * 65536;   // (b*64+l)*P*V
    float4 acc = float4{0.f,0.f,0.f,0.f};
    for (int it = 0; it < 64; ++it) {
        float4 d = *(const float4*)(base + (pr + it*16) * 64 + c4 * 4);
        acc.x += d.x; acc.y += d.y; acc.z += d.z; acc.w += d.w;
    }
    __shared__ float red[16][68];
    *(float4*)&red[pr][c4 * 4] = acc;
    __syncthreads();
    if (t < 64) {
        float s = 0.f;
#pragma unroll
        for (int w = 0; w < 16; ++w) s += red[w][t];
        s *= (1.f/64.f);
        float sn = s * s;
#pragma unroll
        for (int off = 32; off >= 1; off >>= 1) sn += __shfl_xor(sn, off);
        vout[blockIdx.x * 64 + t] = s * sqrtf(sn) / (1.f + sn);
    }
}

// ---------------------------------------------------------------- routing pass (B or C):
// per p: b_new[l] = (read_b ? bij : 0) + v_in[b][l][:].u_hat[b][l][p][:] ; c = softmax_l(b_new);
// s += c[l]*u_hat. Grid: 4 b x 128 chunks of 8 p. Partials reduced later.
__global__ __launch_bounds__(256) void k_route(const float* __restrict__ uhat,
                                               const float* __restrict__ vin,
                                               float* __restrict__ bij,
                                               float* __restrict__ part, const int read_b) {
    const int blk = blockIdx.x;
    const int b = blk >> 7, ch = blk & 127;
    const int p0 = ch * 8;
    const int t = threadIdx.x;
    const int v = t & 63, w = t >> 6;
    __shared__ float uh[64][68];
    __shared__ float vs[64][68];
    __shared__ float bl[64];
    __shared__ float cl[64];
    {
        const float* src = vin + b * 4096;
        for (int i = t; i < 1024; i += 256) {
            float4 d = *(const float4*)(src + i * 4);
            int l = i >> 4, v0 = (i & 15) * 4;
            vs[l][v0] = d.x; vs[l][v0+1] = d.y; vs[l][v0+2] = d.z; vs[l][v0+3] = d.w;
        }
    }
    float sacc[16];
#pragma unroll
    for (int j = 0; j < 16; ++j) sacc[j] = 0.f;

    for (int pp = 0; pp < 8; ++pp) {
        const int p = p0 + pp;
        __syncthreads();
        const float* src = uhat + (size_t)b * 4194304 + (size_t)p * 64;   // b*L*P*V
        for (int i = t; i < 1024; i += 256) {
            int l = i >> 4, v0 = (i & 15) * 4;
            float4 d = *(const float4*)(src + (size_t)l * 65536 + v0);
            uh[l][v0] = d.x; uh[l][v0+1] = d.y; uh[l][v0+2] = d.z; uh[l][v0+3] = d.w;
        }
        __syncthreads();
#pragma unroll
        for (int i = 0; i < 16; ++i) {
            const int l = w * 16 + i;
            float prod = uh[l][v] * vs[l][v];
#pragma unroll
            for (int off = 32; off >= 1; off >>= 1) prod += __shfl_xor(prod, off);
            if (v == 0) {
                float bb = prod;
                if (read_b) bb += bij[(b * 64 + l) * 1024 + p];
                bl[l] = bb;
                if (!read_b) bij[(b * 64 + l) * 1024 + p] = bb;
            }
        }
        __syncthreads();
        if (w == 0) {                               // softmax over l (lane = l)
            float xv = bl[v];
            float m = xv;
#pragma unroll
            for (int off = 32; off >= 1; off >>= 1) m = fmaxf(m, __shfl_xor(m, off));
            float e = expf(xv - m);
            float sgm = e;
#pragma unroll
            for (int off = 32; off >= 1; off >>= 1) sgm += __shfl_xor(sgm, off);
            cl[v] = e / sgm;
        }
        __syncthreads();
#pragma unroll
        for (int j = 0; j < 16; ++j) {
            const int l = j * 4 + w;
            sacc[j] = fmaf(cl[l], uh[l][v], sacc[j]);
        }
    }
#pragma unroll
    for (int j = 0; j < 16; ++j) {
        const int l = j * 4 + w;
        part[((size_t)(b * 128 + ch) * 64 + l) * 64 + v] = sacc[j];
    }
}

// ---------------------------------------------------------------- reduce partials + squash (+ presence)
__global__ void k_red_squash(const float* __restrict__ part, float* __restrict__ vout,
                             float* __restrict__ pres) {
    const int wv = blockIdx.x;                      // b*64 + l
    const int b = wv >> 6, l = wv & 63;
    const int v = threadIdx.x;
    float acc = 0.f;
    for (int ch = 0; ch < 128; ++ch) acc += part[((size_t)(b * 128 + ch) * 64 + l) * 64 + v];
    float sn = acc * acc;
#pragma unroll
    for (int off = 32; off >= 1; off >>= 1) sn += __shfl_xor(sn, off);
    vout[wv * 64 + v] = acc * sqrtf(sn) / (1.f + sn);
    if (pres != nullptr && v == 0) pres[wv] = sn / (1.f + sn);   // ||squash(s)|| = sn/(1+sn)
}

// ---------------------------------------------------------------- classifier head
__global__ void k_logits(const float* __restrict__ vj, const float* __restrict__ fcw,
                         const float* __restrict__ fcb, float* __restrict__ out) {
    int wv = blockIdx.x * 4 + (threadIdx.x >> 6);   // 0..159
    int lane = threadIdx.x & 63;
    int b = wv / 40, o = wv % 40;
    const float* xv = vj + b * 4096;
    const float* wr = fcw + (size_t)o * 4096;
    float acc = 0.f;
    for (int i = lane; i < 4096; i += 64) acc = fmaf(xv[i], wr[i], acc);
#pragma unroll
    for (int off = 32; off >= 1; off >>= 1) acc += __shfl_xor(acc, off);
    if (lane == 0) out[b * 40 + o] = acc + fcb[o];
}

extern "C" void kernel_launch(void* const* d_in, const int* in_sizes, int n_in,
                              void* d_out, int out_size, void* d_ws, size_t ws_size,
                              hipStream_t stream) {
    const float* x   = (const float*)d_in[0];
    const float* w1  = (const float*)d_in[1];
    // d_in[2] = b1: cancels under batch-norm
    const float* g1  = (const float*)d_in[3];
    const float* be1 = (const float*)d_in[4];
    const float* w2  = (const float*)d_in[5];
    // d_in[6] = b2: cancels
    const float* g2  = (const float*)d_in[7];
    const float* be2 = (const float*)d_in[8];
    const float* w3  = (const float*)d_in[9];
    // d_in[10] = b3: cancels
    const float* g3  = (const float*)d_in[11];
    const float* be3 = (const float*)d_in[12];
    const float* Wr  = (const float*)d_in[13];
    const float* fcw = (const float*)d_in[14];
    const float* fcb = (const float*)d_in[15];
    float* out = (float*)d_out;

    float* ws       = (float*)d_ws;
    float* y1       = ws;                   // [64][8192]   (BN/ReLU in place)
    float* y2       = y1 + 524288;          // [128][8192]
    float* mean1    = y2 + 1048576;         // 64
    float* inv1     = mean1 + 64;           // 64
    float* mean2    = inv1 + 64;            // 128
    float* inv2     = mean2 + 128;          // 128
    float* umax     = inv2 + 128;           // [4][16384]
    float* umin     = umax + 65536;         // [4][16384]
    float* usum_b   = umin + 65536;         // [4][16384] per-b partials
    float* usumsq_b = usum_b + 65536;       // [4][16384]
    float* u        = usumsq_b + 65536;     // [4][1024][16]
    float* v1       = u + 65536;            // [4][64][64]
    float* v2       = v1 + 16384;
    float* vj       = v2 + 16384;
    float* bij      = vj + 16384;           // [4][64][1024]
    float* part     = bij + 262144;         // [4][128][64][64] (8 MB)
    float* uhat     = part + 2097152;       // [4][64][1024][64]  (64 MB)
    // fp16 staging buffers alias the uhat region: dead before k_uhat writes it.
    _Float16* w3h = (_Float16*)uhat;        // [16384][128]
    _Float16* w3l = w3h + 2097152;
    _Float16* h2h = w3l + 2097152;          // [8192][128] (bn-major)
    _Float16* h2l = h2h + 1048576;

    k_conv1<<<dim3(32, 64), 256, 0, stream>>>(x, w1, y1);
    k_stats<<<64, 256, 0, stream>>>(y1, mean1, inv1);
    k_bnrelu<<<512, 256, 0, stream>>>(y1, y1, mean1, inv1, g1, be1, 131072);
    k_conv2<<<dim3(8, 16), 256, 0, stream>>>(y1, w2, y2);
    k_stats<<<128, 256, 0, stream>>>(y2, mean2, inv2);
    k_split_w3<<<2048, 256, 0, stream>>>(w3, w3h, w3l);
    k_h2t_split<<<dim3(128, 2), 256, 0, stream>>>(y2, mean2, inv2, g2, be2, h2h, h2l);
    k_caps<<<dim3(256, 4), 256, 0, stream>>>(w3h, w3l, h2h, h2l, umax, umin, usum_b, usumsq_b);
    k_u<<<16, 256, 0, stream>>>(umax, umin, usum_b, usumsq_b, g3, be3, u);
    k_uhat<<<dim3(256, 64), 256, 0, stream>>>(Wr, u, uhat);
    k_passA<<<256, 256, 0, stream>>>(uhat, v1);
    k_route<<<512, 256, 0, stream>>>(uhat, v1, bij, part, 0);
    k_red_squash<<<256, 64, 0, stream>>>(part, v2, nullptr);
    k_route<<<512, 256, 0, stream>>>(uhat, v2, bij, part, 1);
    k_red_squash<<<256, 64, 0, stream>>>(part, vj, out + 160);
    k_logits<<<40, 256, 0, stream>>>(vj, fcw, fcb, out);
}

// Round 4
// 709.100 us; speedup vs baseline: 1.9405x; 1.0828x over previous
//
#include <hip/hip_runtime.h>
#include <math.h>

// Dims (fixed by setup_inputs): B=4, N=2048, C1=64, C2=128, P=1024, Q=16, L=64, V=64, OUT=40
// BN = B*N = 8192, QP = Q*P = 16384
#define BN_EPS 1e-5f

typedef __attribute__((ext_vector_type(8))) _Float16 half8;
typedef __attribute__((ext_vector_type(4))) float f32x4;
#define SPLIT_S  2048.0f
#define INV_S    (1.0f/2048.0f)

// ---------------------------------------------------------------- conv1 (bias dropped: cancels in BN)
__global__ void k_conv1(const float* __restrict__ x, const float* __restrict__ w1,
                        float* __restrict__ y1) {
    int i = blockIdx.x * 256 + threadIdx.x;        // 0..131071 : (o, bn/4)
    int o = i >> 11;                               // wave-uniform (2048-runs)
    int bn4 = (i & 2047) * 4;
    int b = bn4 >> 11, n = bn4 & 2047;
    const float* xb = x + (size_t)b * 6144 + n;
    float4 x0 = *(const float4*)(xb);
    float4 x1 = *(const float4*)(xb + 2048);
    float4 x2 = *(const float4*)(xb + 4096);
    float wa = w1[o*3+0], wb = w1[o*3+1], wc = w1[o*3+2];
    float4 r;
    r.x = wa*x0.x + wb*x1.x + wc*x2.x;
    r.y = wa*x0.y + wb*x1.y + wc*x2.y;
    r.z = wa*x0.z + wb*x1.z + wc*x2.z;
    r.w = wa*x0.w + wb*x1.w + wc*x2.w;
    *(float4*)(y1 + o * 8192 + bn4) = r;
}

// ---------------------------------------------------------------- per-channel batch stats over 8192 elems
__global__ void k_stats(const float* __restrict__ y, float* __restrict__ mean,
                        float* __restrict__ inv) {
    int c = blockIdx.x, t = threadIdx.x;
    float s = 0.f, ss = 0.f;
    const float4* src = (const float4*)(y + c * 8192);
    for (int i = t; i < 2048; i += 256) {
        float4 v = src[i];
        s += v.x + v.y + v.z + v.w;
        ss = fmaf(v.x, v.x, fmaf(v.y, v.y, fmaf(v.z, v.z, fmaf(v.w, v.w, ss))));
    }
    __shared__ float rs[256], rss[256];
    rs[t] = s; rss[t] = ss;
    __syncthreads();
    for (int off = 128; off > 0; off >>= 1) {
        if (t < off) { rs[t] += rs[t+off]; rss[t] += rss[t+off]; }
        __syncthreads();
    }
    if (t == 0) {
        float m = rs[0] * (1.f/8192.f);
        float var = rss[0] * (1.f/8192.f) - m*m;
        mean[c] = m;
        inv[c]  = rsqrtf(var + BN_EPS);
    }
}

// ---------------------------------------------------------------- BN + ReLU (float4, in-place ok)
__global__ void k_bnrelu(const float* __restrict__ y, float* __restrict__ h,
                         const float* __restrict__ mean, const float* __restrict__ inv,
                         const float* __restrict__ g, const float* __restrict__ be, int total4) {
    int i = blockIdx.x * 256 + threadIdx.x;
    if (i >= total4) return;
    int c = i >> 11;                               // (i*4) / 8192
    float sc = inv[c] * g[c], sh = be[c] - mean[c] * sc;
    float4 v = *(const float4*)(y + i * 4);
    v.x = fmaxf(fmaf(v.x, sc, sh), 0.f);
    v.y = fmaxf(fmaf(v.y, sc, sh), 0.f);
    v.z = fmaxf(fmaf(v.z, sc, sh), 0.f);
    v.w = fmaxf(fmaf(v.w, sc, sh), 0.f);
    *(float4*)(h + i * 4) = v;
}

// ---------------------------------------------------------------- conv2: y2[o][bn] = sum_c w2[o][c] h1[c][bn]
__global__ __launch_bounds__(256) void k_conv2(const float* __restrict__ h1,
                                               const float* __restrict__ w2,
                                               float* __restrict__ y2) {
    int bn0 = (blockIdx.x * 256 + threadIdx.x) * 4;
    int og0 = blockIdx.y * 4;
    float4 acc[4];
#pragma unroll
    for (int j = 0; j < 4; ++j) acc[j] = float4{0.f,0.f,0.f,0.f};
    for (int c = 0; c < 64; ++c) {
        float4 hv = *(const float4*)(h1 + c*8192 + bn0);
#pragma unroll
        for (int j = 0; j < 4; ++j) {
            float w = w2[(og0+j)*64 + c];
            acc[j].x = fmaf(w, hv.x, acc[j].x); acc[j].y = fmaf(w, hv.y, acc[j].y);
            acc[j].z = fmaf(w, hv.z, acc[j].z); acc[j].w = fmaf(w, hv.w, acc[j].w);
        }
    }
#pragma unroll
    for (int j = 0; j < 4; ++j) *(float4*)(y2 + (og0+j)*8192 + bn0) = acc[j];
}

// ---------------------------------------------------------------- split w3 fp32 -> fp16 hi + scaled lo
__global__ void k_split_w3(const float* __restrict__ w, _Float16* __restrict__ hi,
                           _Float16* __restrict__ lo) {
    int base = blockIdx.x * 256 + threadIdx.x;     // grid-stride over 4 chunks
#pragma unroll
    for (int it = 0; it < 4; ++it) {
        int i = (base + it * 131072) * 4;
        float4 d = *reinterpret_cast<const float4*>(w + i);
        float vs[4] = {d.x, d.y, d.z, d.w};
#pragma unroll
        for (int j = 0; j < 4; ++j) {
            _Float16 h = (_Float16)vs[j];
            hi[i + j] = h;
            lo[i + j] = (_Float16)((vs[j] - (float)h) * SPLIT_S);
        }
    }
}

// ---------------------------------------------------------------- BN2+ReLU fused with transpose+split:
// h2t[bn][c] (hi/lo fp16) from y2[c][bn] fp32. 64x64 LDS tile transpose.
__global__ __launch_bounds__(256) void k_h2t_split(const float* __restrict__ y2,
        const float* __restrict__ mean, const float* __restrict__ inv,
        const float* __restrict__ g, const float* __restrict__ be,
        _Float16* __restrict__ hi, _Float16* __restrict__ lo) {
    __shared__ float tile[64][65];
    const int t = threadIdx.x;
    const int bn0 = blockIdx.x * 64, c0 = blockIdx.y * 64;
#pragma unroll
    for (int r = 0; r < 16; ++r) {
        int idx = r * 256 + t;
        int cl = idx >> 6, bnl = idx & 63;          // c wave-uniform -> scalar stat loads
        int c = c0 + cl;
        float v = y2[(size_t)c * 8192 + bn0 + bnl];
        v = (v - mean[c]) * inv[c] * g[c] + be[c];
        tile[cl][bnl] = v > 0.f ? v : 0.f;
    }
    __syncthreads();
#pragma unroll
    for (int r = 0; r < 16; ++r) {
        int idx = r * 256 + t;
        int bnl = idx >> 6, cl = idx & 63;
        float v = tile[cl][bnl];
        _Float16 h = (_Float16)v;
        size_t o = (size_t)(bn0 + bnl) * 128 + c0 + cl;
        hi[o] = h;
        lo[o] = (_Float16)((v - (float)h) * SPLIT_S);
    }
}

// ---------------------------------------------------------------- THE BIG ONE v4.
// u[qp][bn] = w3[qp][:].h2[:][bn], K=128, fp16x3 split MFMA.
// Block: 128 rows, 4 waves split M (2 m-tiles each -> A = 16 half8 = 64 VGPR,
// fits without remat). B tile (16 cols, hi+lo) staged in LDS in FRAGMENT
// ORDER (lane-linear: conflict-free b128 writes & reads), double-buffered,
// software-pipelined (global loads for nt+1 issued before MFMA on nt).
// Rows exclusive per wave -> stats complete in-wave. Grid (128, 4b).
__global__ __launch_bounds__(256, 2) void k_caps(
        const _Float16* __restrict__ w3h, const _Float16* __restrict__ w3l,
        const _Float16* __restrict__ h2h, const _Float16* __restrict__ h2l,
        float* __restrict__ umax, float* __restrict__ umin,
        float* __restrict__ usum_b, float* __restrict__ usumsq_b) {
    const int lane = threadIdx.x & 63, wave = threadIdx.x >> 6;
    const int b = blockIdx.y;
    const int mrow = blockIdx.x * 128 + wave * 32;
    const int r16 = lane & 15, kq = lane >> 4;     // frag: row/col=lane&15, k=kq*8+j

    __shared__ _Float16 Bs[2][8][64][8];           // [buf][ks*2+h][lane][j] 16 KB

    half8 Ah[2][4], Al[2][4];
#pragma unroll
    for (int mt = 0; mt < 2; ++mt) {
        const size_t base = (size_t)(mrow + mt*16 + r16) * 128 + kq * 8;
#pragma unroll
        for (int ks = 0; ks < 4; ++ks) {
            Ah[mt][ks] = *reinterpret_cast<const half8*>(w3h + base + ks*32);
            Al[mt][ks] = *reinterpret_cast<const half8*>(w3l + base + ks*32);
        }
    }
    float mx[2][4], mn[2][4], sm[2][4], sq[2][4];
#pragma unroll
    for (int mt = 0; mt < 2; ++mt)
#pragma unroll
        for (int r = 0; r < 4; ++r) {
            mx[mt][r] = -3.4e38f; mn[mt][r] = 3.4e38f; sm[mt][r] = 0.f; sq[mt][r] = 0.f;
        }

    // stage unit: u = wave*2+i covers (ks = u>>1, hi/lo = u&1); lane-linear dst.
    const int u0 = wave * 2;
    const int ks0 = u0 >> 1;                       // = wave
    // src pointers for this thread's two units (h = 0 then 1)
    const size_t srow = (size_t)(b*2048 + r16) * 128 + ks0 * 32 + kq * 8;

    { // prologue: stage nt=0 into buf 0
        *reinterpret_cast<half8*>(&Bs[0][u0  ][lane][0]) = *reinterpret_cast<const half8*>(h2h + srow);
        *reinterpret_cast<half8*>(&Bs[0][u0+1][lane][0]) = *reinterpret_cast<const half8*>(h2l + srow);
    }
    __syncthreads();

    for (int nt = 0; nt < 128; ++nt) {
        const int buf = nt & 1;
        // issue global loads for nt+1 early (redundant reload at nt=127)
        const int ntn = (nt + 1 < 128) ? nt + 1 : nt;
        const size_t snext = srow + (size_t)ntn * 16 * 128;
        half8 g0 = *reinterpret_cast<const half8*>(h2h + snext);
        half8 g1 = *reinterpret_cast<const half8*>(h2l + snext);

        f32x4 acc[2], accx[2];
#pragma unroll
        for (int mt = 0; mt < 2; ++mt) { acc[mt] = f32x4{0.f,0.f,0.f,0.f}; accx[mt] = f32x4{0.f,0.f,0.f,0.f}; }
#pragma unroll
        for (int ks = 0; ks < 4; ++ks) {
            half8 Bh = *reinterpret_cast<const half8*>(&Bs[buf][ks*2  ][lane][0]);
            half8 Bl = *reinterpret_cast<const half8*>(&Bs[buf][ks*2+1][lane][0]);
#pragma unroll
            for (int mt = 0; mt < 2; ++mt) {
                acc[mt]  = __builtin_amdgcn_mfma_f32_16x16x32_f16(Ah[mt][ks], Bh, acc[mt], 0, 0, 0);
                accx[mt] = __builtin_amdgcn_mfma_f32_16x16x32_f16(Ah[mt][ks], Bl, accx[mt], 0, 0, 0);
                accx[mt] = __builtin_amdgcn_mfma_f32_16x16x32_f16(Al[mt][ks], Bh, accx[mt], 0, 0, 0);
            }
        }
#pragma unroll
        for (int mt = 0; mt < 2; ++mt)
#pragma unroll
            for (int r = 0; r < 4; ++r) {
                float v = fmaf(accx[mt][r], INV_S, acc[mt][r]);   // u element (fp32-class)
                mx[mt][r] = fmaxf(mx[mt][r], v);
                mn[mt][r] = fminf(mn[mt][r], v);
                sm[mt][r] += v;
                sq[mt][r] = fmaf(v, v, sq[mt][r]);
            }
        // write next tile into the other buffer
        *reinterpret_cast<half8*>(&Bs[buf^1][u0  ][lane][0]) = g0;
        *reinterpret_cast<half8*>(&Bs[buf^1][u0+1][lane][0]) = g1;
        __syncthreads();
    }

    // reduce over the 16 column lanes (C/D: col=lane&15, row=kq*4+reg)
#pragma unroll
    for (int off = 8; off >= 1; off >>= 1)
#pragma unroll
        for (int mt = 0; mt < 2; ++mt)
#pragma unroll
            for (int r = 0; r < 4; ++r) {
                mx[mt][r] = fmaxf(mx[mt][r], __shfl_xor(mx[mt][r], off));
                mn[mt][r] = fminf(mn[mt][r], __shfl_xor(mn[mt][r], off));
                sm[mt][r] += __shfl_xor(sm[mt][r], off);
                sq[mt][r] += __shfl_xor(sq[mt][r], off);
            }
    if (r16 == 0) {
#pragma unroll
        for (int mt = 0; mt < 2; ++mt)
#pragma unroll
            for (int r = 0; r < 4; ++r) {
                int qp = mrow + mt*16 + kq*4 + r;
                umax[b*16384 + qp]     = mx[mt][r];
                umin[b*16384 + qp]     = mn[mt][r];
                usum_b[b*16384 + qp]   = sm[mt][r];
                usumsq_b[b*16384 + qp] = sq[mt][r];
            }
    }
}

// ---------------------------------------------------------------- BN3 (analytic, sign-safe) + squash over Q
__global__ void k_u(const float* __restrict__ umax, const float* __restrict__ umin,
                    const float* __restrict__ usum_b, const float* __restrict__ usumsq_b,
                    const float* __restrict__ g3, const float* __restrict__ be3,
                    float* __restrict__ u) {
    int tg = blockIdx.x * 256 + threadIdx.x;       // 0..4095 : (b,p)
    int b = tg >> 10, p = tg & 1023;
    float ub[16]; float sn = 0.f;
#pragma unroll
    for (int q = 0; q < 16; ++q) {
        int qp = q * 1024 + p;
        float s  = usum_b[qp] + usum_b[16384+qp] + usum_b[32768+qp] + usum_b[49152+qp];
        float ss = usumsq_b[qp] + usumsq_b[16384+qp] + usumsq_b[32768+qp] + usumsq_b[49152+qp];
        float mean  = s * (1.f/8192.f);
        float var   = ss * (1.f/8192.f) - mean*mean;
        float scale = g3[qp] * rsqrtf(var + BN_EPS);
        float val = (scale >= 0.f) ? umax[b*16384 + qp] : umin[b*16384 + qp];   // bn monotone in sign(scale)
        float vb = (val - mean) * scale + be3[qp];
        ub[q] = vb; sn = fmaf(vb, vb, sn);
    }
    float f = sqrtf(sn) / (1.f + sn);              // squash factor
#pragma unroll
    for (int q = 0; q < 16; ++q) u[tg*16 + q] = ub[q] * f;
}

// ---------------------------------------------------------------- u_hat[b][l][p][v] = sum_q Wr[l][p][v][q] u[b][p][q]
// 32 p per block (8 sub-tiles of 4): fat blocks, HBM-bound on Wr.
__global__ __launch_bounds__(256) void k_uhat(const float* __restrict__ Wr,
                                              const float* __restrict__ u,
                                              float* __restrict__ uhat) {
    const int t = threadIdx.x;
    const int l = blockIdx.y;
    __shared__ float wr[4][16][68];                // [p][q][v] padded
    __shared__ float us[4][4][16];                 // [p][b][q]
    const int bb = t >> 6, v = t & 63;
    for (int sub = 0; sub < 8; ++sub) {
        const int p0 = blockIdx.x * 32 + sub * 4;
        const float* src = Wr + ((size_t)l * 1024 + p0) * 1024;
        if (sub) __syncthreads();                  // LDS reuse guard
#pragma unroll
        for (int it = 0; it < 4; ++it) {
            float4 d = *(const float4*)(src + (it*256 + t) * 4);
            int vv = t >> 2, q0 = (t & 3) * 4;     // p = it (wave-uniform)
            wr[it][q0  ][vv] = d.x; wr[it][q0+1][vv] = d.y;
            wr[it][q0+2][vv] = d.z; wr[it][q0+3][vv] = d.w;
        }
        {
            int p = t >> 6, b2 = (t >> 4) & 3, q = t & 15;
            us[p][b2][q] = u[((size_t)b2 * 1024 + p0 + p) * 16 + q];
        }
        __syncthreads();
#pragma unroll
        for (int p = 0; p < 4; ++p) {
            float acc = 0.f;
#pragma unroll
            for (int q = 0; q < 16; ++q) acc = fmaf(wr[p][q][v], us[p][bb][q], acc);
            uhat[((size_t)(bb * 64 + l) * 1024 + p0 + p) * 64 + v] = acc;
        }
    }
}

// ---------------------------------------------------------------- pass A: s1 = (1/64) sum_p u_hat, squash fused
__global__ void k_passA(const float* __restrict__ uhat, float* __restrict__ vout) {
    const int t = threadIdx.x;
    const int c4 = t & 15, pr = t >> 4;            // v0 = c4*4, p = pr + 16*it
    const float* base = uhat + (size_t)blockIdx.x * 65536;   // (b*64+l)*P*V
    float4 acc = float4{0.f,0.f,0.f,0.f};
    for (int it = 0; it < 64; ++it) {
        float4 d = *(const float4*)(base + (pr + it*16) * 64 + c4 * 4);
        acc.x += d.x; acc.y += d.y; acc.z += d.z; acc.w += d.w;
    }
    __shared__ float red[16][68];
    *(float4*)&red[pr][c4 * 4] = acc;
    __syncthreads();
    if (t < 64) {
        float s = 0.f;
#pragma unroll
        for (int w = 0; w < 16; ++w) s += red[w][t];
        s *= (1.f/64.f);
        float sn = s * s;
#pragma unroll
        for (int off = 32; off >= 1; off >>= 1) sn += __shfl_xor(sn, off);
        vout[blockIdx.x * 64 + t] = s * sqrtf(sn) / (1.f + sn);
    }
}

// ---------------------------------------------------------------- routing pass (B or C):
// per p: b_new[l] = (read_b ? bij : 0) + v_in[b][l][:].u_hat[b][l][p][:] ; c = softmax_l(b_new);
// s += c[l]*u_hat. Grid: 4 b x 128 chunks of 8 p. Partials reduced later.
__global__ __launch_bounds__(256) void k_route(const float* __restrict__ uhat,
                                               const float* __restrict__ vin,
                                               float* __restrict__ bij,
                                               float* __restrict__ part, const int read_b) {
    const int blk = blockIdx.x;
    const int b = blk >> 7, ch = blk & 127;
    const int p0 = ch * 8;
    const int t = threadIdx.x;
    const int v = t & 63, w = t >> 6;
    __shared__ float uh[64][68];
    __shared__ float vs[64][68];
    __shared__ float bl[64];
    __shared__ float cl[64];
    {
        const float* src = vin + b * 4096;
        for (int i = t; i < 1024; i += 256) {
            float4 d = *(const float4*)(src + i * 4);
            int l = i >> 4, v0 = (i & 15) * 4;
            vs[l][v0] = d.x; vs[l][v0+1] = d.y; vs[l][v0+2] = d.z; vs[l][v0+3] = d.w;
        }
    }
    float sacc[16];
#pragma unroll
    for (int j = 0; j < 16; ++j) sacc[j] = 0.f;

    for (int pp = 0; pp < 8; ++pp) {
        const int p = p0 + pp;
        __syncthreads();
        const float* src = uhat + (size_t)b * 4194304 + (size_t)p * 64;   // b*L*P*V
        for (int i = t; i < 1024; i += 256) {
            int l = i >> 4, v0 = (i & 15) * 4;
            float4 d = *(const float4*)(src + (size_t)l * 65536 + v0);
            uh[l][v0] = d.x; uh[l][v0+1] = d.y; uh[l][v0+2] = d.z; uh[l][v0+3] = d.w;
        }
        __syncthreads();
#pragma unroll
        for (int i = 0; i < 16; ++i) {
            const int l = w * 16 + i;
            float prod = uh[l][v] * vs[l][v];
#pragma unroll
            for (int off = 32; off >= 1; off >>= 1) prod += __shfl_xor(prod, off);
            if (v == 0) {
                float bb = prod;
                if (read_b) bb += bij[(b * 64 + l) * 1024 + p];
                bl[l] = bb;
                if (!read_b) bij[(b * 64 + l) * 1024 + p] = bb;
            }
        }
        __syncthreads();
        if (w == 0) {                               // softmax over l (lane = l)
            float xv = bl[v];
            float m = xv;
#pragma unroll
            for (int off = 32; off >= 1; off >>= 1) m = fmaxf(m, __shfl_xor(m, off));
            float e = expf(xv - m);
            float sgm = e;
#pragma unroll
            for (int off = 32; off >= 1; off >>= 1) sgm += __shfl_xor(sgm, off);
            cl[v] = e / sgm;
        }
        __syncthreads();
#pragma unroll
        for (int j = 0; j < 16; ++j) {
            const int l = j * 4 + w;
            sacc[j] = fmaf(cl[l], uh[l][v], sacc[j]);
        }
    }
#pragma unroll
    for (int j = 0; j < 16; ++j) {
        const int l = j * 4 + w;
        part[((size_t)(b * 128 + ch) * 64 + l) * 64 + v] = sacc[j];
    }
}

// ---------------------------------------------------------------- reduce partials + squash (+ presence)
__global__ void k_red_squash(const float* __restrict__ part, float* __restrict__ vout,
                             float* __restrict__ pres) {
    const int wv = blockIdx.x;                      // b*64 + l
    const int b = wv >> 6, l = wv & 63;
    const int v = threadIdx.x;
    float acc = 0.f;
    for (int ch = 0; ch < 128; ++ch) acc += part[((size_t)(b * 128 + ch) * 64 + l) * 64 + v];
    float sn = acc * acc;
#pragma unroll
    for (int off = 32; off >= 1; off >>= 1) sn += __shfl_xor(sn, off);
    vout[wv * 64 + v] = acc * sqrtf(sn) / (1.f + sn);
    if (pres != nullptr && v == 0) pres[wv] = sn / (1.f + sn);   // ||squash(s)|| = sn/(1+sn)
}

// ---------------------------------------------------------------- classifier head
__global__ void k_logits(const float* __restrict__ vj, const float* __restrict__ fcw,
                         const float* __restrict__ fcb, float* __restrict__ out) {
    int wv = blockIdx.x * 4 + (threadIdx.x >> 6);   // 0..159
    int lane = threadIdx.x & 63;
    int b = wv / 40, o = wv % 40;
    const float* xv = vj + b * 4096;
    const float* wr = fcw + (size_t)o * 4096;
    float acc = 0.f;
    for (int i = lane; i < 4096; i += 64) acc = fmaf(xv[i], wr[i], acc);
#pragma unroll
    for (int off = 32; off >= 1; off >>= 1) acc += __shfl_xor(acc, off);
    if (lane == 0) out[b * 40 + o] = acc + fcb[o];
}

extern "C" void kernel_launch(void* const* d_in, const int* in_sizes, int n_in,
                              void* d_out, int out_size, void* d_ws, size_t ws_size,
                              hipStream_t stream) {
    const float* x   = (const float*)d_in[0];
    const float* w1  = (const float*)d_in[1];
    // d_in[2] = b1: cancels under batch-norm
    const float* g1  = (const float*)d_in[3];
    const float* be1 = (const float*)d_in[4];
    const float* w2  = (const float*)d_in[5];
    // d_in[6] = b2: cancels
    const float* g2  = (const float*)d_in[7];
    const float* be2 = (const float*)d_in[8];
    const float* w3  = (const float*)d_in[9];
    // d_in[10] = b3: cancels
    const float* g3  = (const float*)d_in[11];
    const float* be3 = (const float*)d_in[12];
    const float* Wr  = (const float*)d_in[13];
    const float* fcw = (const float*)d_in[14];
    const float* fcb = (const float*)d_in[15];
    float* out = (float*)d_out;

    float* ws       = (float*)d_ws;
    float* y1       = ws;                   // [64][8192]   (BN/ReLU in place)
    float* y2       = y1 + 524288;          // [128][8192]
    float* mean1    = y2 + 1048576;         // 64
    float* inv1     = mean1 + 64;           // 64
    float* mean2    = inv1 + 64;            // 128
    float* inv2     = mean2 + 128;          // 128
    float* umax     = inv2 + 128;           // [4][16384]
    float* umin     = umax + 65536;         // [4][16384]
    float* usum_b   = umin + 65536;         // [4][16384] per-b partials
    float* usumsq_b = usum_b + 65536;       // [4][16384]
    float* u        = usumsq_b + 65536;     // [4][1024][16]
    float* v1       = u + 65536;            // [4][64][64]
    float* v2       = v1 + 16384;
    float* vj       = v2 + 16384;
    float* bij      = vj + 16384;           // [4][64][1024]
    float* part     = bij + 262144;         // [4][128][64][64] (8 MB)
    float* uhat     = part + 2097152;       // [4][64][1024][64]  (64 MB)
    // fp16 staging buffers alias the uhat region: dead before k_uhat writes it.
    _Float16* w3h = (_Float16*)uhat;        // [16384][128]
    _Float16* w3l = w3h + 2097152;
    _Float16* h2h = w3l + 2097152;          // [8192][128] (bn-major)
    _Float16* h2l = h2h + 1048576;

    k_conv1<<<512, 256, 0, stream>>>(x, w1, y1);
    k_stats<<<64, 256, 0, stream>>>(y1, mean1, inv1);
    k_bnrelu<<<512, 256, 0, stream>>>(y1, y1, mean1, inv1, g1, be1, 131072);
    k_conv2<<<dim3(8, 32), 256, 0, stream>>>(y1, w2, y2);
    k_stats<<<128, 256, 0, stream>>>(y2, mean2, inv2);
    k_split_w3<<<512, 256, 0, stream>>>(w3, w3h, w3l);
    k_h2t_split<<<dim3(128, 2), 256, 0, stream>>>(y2, mean2, inv2, g2, be2, h2h, h2l);
    k_caps<<<dim3(128, 4), 256, 0, stream>>>(w3h, w3l, h2h, h2l, umax, umin, usum_b, usumsq_b);
    k_u<<<16, 256, 0, stream>>>(umax, umin, usum_b, usumsq_b, g3, be3, u);
    k_uhat<<<dim3(32, 64), 256, 0, stream>>>(Wr, u, uhat);
    k_passA<<<256, 256, 0, stream>>>(uhat, v1);
    k_route<<<512, 256, 0, stream>>>(uhat, v1, bij, part, 0);
    k_red_squash<<<256, 64, 0, stream>>>(part, v2, nullptr);
    k_route<<<512, 256, 0, stream>>>(uhat, v2, bij, part, 1);
    k_red_squash<<<256, 64, 0, stream>>>(part, vj, out + 160);
    k_logits<<<40, 256, 0, stream>>>(vj, fcw, fcb, out);
}

// Round 5
// 694.228 us; speedup vs baseline: 1.9820x; 1.0214x over previous
//
#include <hip/hip_runtime.h>
#include <math.h>

// Dims (fixed by setup_inputs): B=4, N=2048, C1=64, C2=128, P=1024, Q=16, L=64, V=64, OUT=40
// BN = B*N = 8192, QP = Q*P = 16384
#define BN_EPS 1e-5f

typedef __attribute__((ext_vector_type(8))) _Float16 half8;
typedef __attribute__((ext_vector_type(4))) float f32x4;
#define SPLIT_S  2048.0f
#define INV_S    (1.0f/2048.0f)

// ---------------------------------------------------------------- conv1 + batch stats fused.
// One block per output channel o; block streams all 8192 bn, writes y1 row,
// reduces sum/sumsq in-block. x (96 KB) is L2-resident across the 64 blocks.
__global__ __launch_bounds__(256) void k_conv1stats(const float* __restrict__ x,
        const float* __restrict__ w1, float* __restrict__ y1,
        float* __restrict__ mean, float* __restrict__ inv) {
    const int o = blockIdx.x, t = threadIdx.x;
    const float wa = w1[o*3+0], wb = w1[o*3+1], wc = w1[o*3+2];
    float s = 0.f, ss = 0.f;
#pragma unroll
    for (int it = 0; it < 8; ++it) {
        int i = it * 256 + t;                      // 0..2047 : bn/4
        int b = i >> 9, n4 = (i & 511) * 4;
        const float* xb = x + (size_t)b * 6144 + n4;
        float4 x0 = *(const float4*)(xb);
        float4 x1 = *(const float4*)(xb + 2048);
        float4 x2 = *(const float4*)(xb + 4096);
        float4 r;
        r.x = wa*x0.x + wb*x1.x + wc*x2.x;
        r.y = wa*x0.y + wb*x1.y + wc*x2.y;
        r.z = wa*x0.z + wb*x1.z + wc*x2.z;
        r.w = wa*x0.w + wb*x1.w + wc*x2.w;
        *(float4*)(y1 + o * 8192 + i * 4) = r;
        s += r.x + r.y + r.z + r.w;
        ss = fmaf(r.x, r.x, fmaf(r.y, r.y, fmaf(r.z, r.z, fmaf(r.w, r.w, ss))));
    }
    __shared__ float rs[256], rss[256];
    rs[t] = s; rss[t] = ss;
    __syncthreads();
    for (int off = 128; off > 0; off >>= 1) {
        if (t < off) { rs[t] += rs[t+off]; rss[t] += rss[t+off]; }
        __syncthreads();
    }
    if (t == 0) {
        float m = rs[0] * (1.f/8192.f);
        float var = rss[0] * (1.f/8192.f) - m*m;
        mean[o] = m;
        inv[o]  = rsqrtf(var + BN_EPS);
    }
}

// ---------------------------------------------------------------- per-channel batch stats (for y2)
__global__ void k_stats(const float* __restrict__ y, float* __restrict__ mean,
                        float* __restrict__ inv) {
    int c = blockIdx.x, t = threadIdx.x;
    float s = 0.f, ss = 0.f;
    const float4* src = (const float4*)(y + c * 8192);
    for (int i = t; i < 2048; i += 256) {
        float4 v = src[i];
        s += v.x + v.y + v.z + v.w;
        ss = fmaf(v.x, v.x, fmaf(v.y, v.y, fmaf(v.z, v.z, fmaf(v.w, v.w, ss))));
    }
    __shared__ float rs[256], rss[256];
    rs[t] = s; rss[t] = ss;
    __syncthreads();
    for (int off = 128; off > 0; off >>= 1) {
        if (t < off) { rs[t] += rs[t+off]; rss[t] += rss[t+off]; }
        __syncthreads();
    }
    if (t == 0) {
        float m = rs[0] * (1.f/8192.f);
        float var = rss[0] * (1.f/8192.f) - m*m;
        mean[c] = m;
        inv[c]  = rsqrtf(var + BN_EPS);
    }
}

// ---------------------------------------------------------------- conv2 with BN1+ReLU fused on load:
// y2[o][bn] = sum_c w2[o][c] relu(bn1(y1[c][bn]))
__global__ __launch_bounds__(256) void k_conv2(const float* __restrict__ y1,
        const float* __restrict__ w2,
        const float* __restrict__ mean1, const float* __restrict__ inv1,
        const float* __restrict__ g1, const float* __restrict__ be1,
        float* __restrict__ y2) {
    __shared__ float sc1[64], sh1[64];
    const int t = threadIdx.x;
    if (t < 64) {
        float sc = inv1[t] * g1[t];
        sc1[t] = sc;
        sh1[t] = be1[t] - mean1[t] * sc;
    }
    __syncthreads();
    int bn0 = (blockIdx.x * 256 + t) * 4;
    int og0 = blockIdx.y * 4;
    float4 acc[4];
#pragma unroll
    for (int j = 0; j < 4; ++j) acc[j] = float4{0.f,0.f,0.f,0.f};
    for (int c = 0; c < 64; ++c) {
        float4 hv = *(const float4*)(y1 + c*8192 + bn0);
        float sc = sc1[c], sh = sh1[c];
        hv.x = fmaxf(fmaf(hv.x, sc, sh), 0.f);
        hv.y = fmaxf(fmaf(hv.y, sc, sh), 0.f);
        hv.z = fmaxf(fmaf(hv.z, sc, sh), 0.f);
        hv.w = fmaxf(fmaf(hv.w, sc, sh), 0.f);
#pragma unroll
        for (int j = 0; j < 4; ++j) {
            float w = w2[(og0+j)*64 + c];
            acc[j].x = fmaf(w, hv.x, acc[j].x); acc[j].y = fmaf(w, hv.y, acc[j].y);
            acc[j].z = fmaf(w, hv.z, acc[j].z); acc[j].w = fmaf(w, hv.w, acc[j].w);
        }
    }
#pragma unroll
    for (int j = 0; j < 4; ++j) *(float4*)(y2 + (og0+j)*8192 + bn0) = acc[j];
}

// ---------------------------------------------------------------- split w3 fp32 -> fp16 hi + scaled lo
__global__ void k_split_w3(const float* __restrict__ w, _Float16* __restrict__ hi,
                           _Float16* __restrict__ lo) {
    int base = blockIdx.x * 256 + threadIdx.x;     // grid-stride over 4 chunks
#pragma unroll
    for (int it = 0; it < 4; ++it) {
        int i = (base + it * 131072) * 4;
        float4 d = *reinterpret_cast<const float4*>(w + i);
        float vs[4] = {d.x, d.y, d.z, d.w};
#pragma unroll
        for (int j = 0; j < 4; ++j) {
            _Float16 h = (_Float16)vs[j];
            hi[i + j] = h;
            lo[i + j] = (_Float16)((vs[j] - (float)h) * SPLIT_S);
        }
    }
}

// ---------------------------------------------------------------- BN2+ReLU fused with transpose+split:
// h2t[bn][c] (hi/lo fp16) from y2[c][bn] fp32. 64x64 LDS tile transpose.
__global__ __launch_bounds__(256) void k_h2t_split(const float* __restrict__ y2,
        const float* __restrict__ mean, const float* __restrict__ inv,
        const float* __restrict__ g, const float* __restrict__ be,
        _Float16* __restrict__ hi, _Float16* __restrict__ lo) {
    __shared__ float tile[64][65];
    const int t = threadIdx.x;
    const int bn0 = blockIdx.x * 64, c0 = blockIdx.y * 64;
#pragma unroll
    for (int r = 0; r < 16; ++r) {
        int idx = r * 256 + t;
        int cl = idx >> 6, bnl = idx & 63;          // c wave-uniform -> scalar stat loads
        int c = c0 + cl;
        float v = y2[(size_t)c * 8192 + bn0 + bnl];
        v = (v - mean[c]) * inv[c] * g[c] + be[c];
        tile[cl][bnl] = v > 0.f ? v : 0.f;
    }
    __syncthreads();
#pragma unroll
    for (int r = 0; r < 16; ++r) {
        int idx = r * 256 + t;
        int bnl = idx >> 6, cl = idx & 63;
        float v = tile[cl][bnl];
        _Float16 h = (_Float16)v;
        size_t o = (size_t)(bn0 + bnl) * 128 + c0 + cl;
        hi[o] = h;
        lo[o] = (_Float16)((v - (float)h) * SPLIT_S);
    }
}

// ---------------------------------------------------------------- THE BIG ONE v5.
// u[qp][bn] = w3[qp][:].h2[:][bn], K=128, fp16x3 split MFMA.
// 4 waves split M (2 m-tiles each, A in regs). 32-col B tiles (2 groups of
// 16) staged in LDS in fragment order, double-buffered: 64 barriers, 48
// MFMA per barrier. Stats (per-b max/min, sum/sq) fused in epilogue.
__global__ __launch_bounds__(256, 2) void k_caps(
        const _Float16* __restrict__ w3h, const _Float16* __restrict__ w3l,
        const _Float16* __restrict__ h2h, const _Float16* __restrict__ h2l,
        float* __restrict__ umax, float* __restrict__ umin,
        float* __restrict__ usum_b, float* __restrict__ usumsq_b) {
    const int lane = threadIdx.x & 63, wave = threadIdx.x >> 6;
    const int b = blockIdx.y;
    const int mrow = blockIdx.x * 128 + wave * 32;
    const int r16 = lane & 15, kq = lane >> 4;     // frag: row/col=lane&15, k=kq*8+j

    __shared__ _Float16 Bs[2][2][8][64][8];        // [buf][g][ks*2+h][lane][j] 32 KB

    half8 Ah[2][4], Al[2][4];
#pragma unroll
    for (int mt = 0; mt < 2; ++mt) {
        const size_t base = (size_t)(mrow + mt*16 + r16) * 128 + kq * 8;
#pragma unroll
        for (int ks = 0; ks < 4; ++ks) {
            Ah[mt][ks] = *reinterpret_cast<const half8*>(w3h + base + ks*32);
            Al[mt][ks] = *reinterpret_cast<const half8*>(w3l + base + ks*32);
        }
    }
    float mx[2][4], mn[2][4], sm[2][4], sq[2][4];
#pragma unroll
    for (int mt = 0; mt < 2; ++mt)
#pragma unroll
        for (int r = 0; r < 4; ++r) {
            mx[mt][r] = -3.4e38f; mn[mt][r] = 3.4e38f; sm[mt][r] = 0.f; sq[mt][r] = 0.f;
        }

    // staging: thread covers units u0=wave*2 (h2h) and u0+1 (h2l), k-off = wave*32+kq*8
    const int u0 = wave * 2;
    const size_t srow = (size_t)(b*2048 + r16) * 128 + wave * 32 + kq * 8;

    { // prologue: stage nt=0 (cols 0..31) into buf 0
#pragma unroll
        for (int g = 0; g < 2; ++g) {
            const size_t a = srow + (size_t)g * 16 * 128;
            *reinterpret_cast<half8*>(&Bs[0][g][u0  ][lane][0]) = *reinterpret_cast<const half8*>(h2h + a);
            *reinterpret_cast<half8*>(&Bs[0][g][u0+1][lane][0]) = *reinterpret_cast<const half8*>(h2l + a);
        }
    }
    __syncthreads();

    for (int nt = 0; nt < 64; ++nt) {              // 32 cols per iter
        const int buf = nt & 1;
        const int ntn = (nt + 1 < 64) ? nt + 1 : nt;
        const size_t snext = srow + (size_t)ntn * 32 * 128;
        half8 g0h = *reinterpret_cast<const half8*>(h2h + snext);
        half8 g0l = *reinterpret_cast<const half8*>(h2l + snext);
        half8 g1h = *reinterpret_cast<const half8*>(h2h + snext + 2048);
        half8 g1l = *reinterpret_cast<const half8*>(h2l + snext + 2048);

#pragma unroll
        for (int g = 0; g < 2; ++g) {
            f32x4 acc[2], accx[2];
#pragma unroll
            for (int mt = 0; mt < 2; ++mt) { acc[mt] = f32x4{0.f,0.f,0.f,0.f}; accx[mt] = f32x4{0.f,0.f,0.f,0.f}; }
#pragma unroll
            for (int ks = 0; ks < 4; ++ks) {
                half8 Bh = *reinterpret_cast<const half8*>(&Bs[buf][g][ks*2  ][lane][0]);
                half8 Bl = *reinterpret_cast<const half8*>(&Bs[buf][g][ks*2+1][lane][0]);
#pragma unroll
                for (int mt = 0; mt < 2; ++mt) {
                    acc[mt]  = __builtin_amdgcn_mfma_f32_16x16x32_f16(Ah[mt][ks], Bh, acc[mt], 0, 0, 0);
                    accx[mt] = __builtin_amdgcn_mfma_f32_16x16x32_f16(Ah[mt][ks], Bl, accx[mt], 0, 0, 0);
                    accx[mt] = __builtin_amdgcn_mfma_f32_16x16x32_f16(Al[mt][ks], Bh, accx[mt], 0, 0, 0);
                }
            }
#pragma unroll
            for (int mt = 0; mt < 2; ++mt)
#pragma unroll
                for (int r = 0; r < 4; ++r) {
                    float v = fmaf(accx[mt][r], INV_S, acc[mt][r]);
                    mx[mt][r] = fmaxf(mx[mt][r], v);
                    mn[mt][r] = fminf(mn[mt][r], v);
                    sm[mt][r] += v;
                    sq[mt][r] = fmaf(v, v, sq[mt][r]);
                }
        }
        // write next tile into the other buffer
        *reinterpret_cast<half8*>(&Bs[buf^1][0][u0  ][lane][0]) = g0h;
        *reinterpret_cast<half8*>(&Bs[buf^1][0][u0+1][lane][0]) = g0l;
        *reinterpret_cast<half8*>(&Bs[buf^1][1][u0  ][lane][0]) = g1h;
        *reinterpret_cast<half8*>(&Bs[buf^1][1][u0+1][lane][0]) = g1l;
        __syncthreads();
    }

    // reduce over the 16 column lanes (C/D: col=lane&15, row=kq*4+reg)
#pragma unroll
    for (int off = 8; off >= 1; off >>= 1)
#pragma unroll
        for (int mt = 0; mt < 2; ++mt)
#pragma unroll
            for (int r = 0; r < 4; ++r) {
                mx[mt][r] = fmaxf(mx[mt][r], __shfl_xor(mx[mt][r], off));
                mn[mt][r] = fminf(mn[mt][r], __shfl_xor(mn[mt][r], off));
                sm[mt][r] += __shfl_xor(sm[mt][r], off);
                sq[mt][r] += __shfl_xor(sq[mt][r], off);
            }
    if (r16 == 0) {
#pragma unroll
        for (int mt = 0; mt < 2; ++mt)
#pragma unroll
            for (int r = 0; r < 4; ++r) {
                int qp = mrow + mt*16 + kq*4 + r;
                umax[b*16384 + qp]     = mx[mt][r];
                umin[b*16384 + qp]     = mn[mt][r];
                usum_b[b*16384 + qp]   = sm[mt][r];
                usumsq_b[b*16384 + qp] = sq[mt][r];
            }
    }
}

// ---------------------------------------------------------------- BN3 (analytic, sign-safe) + squash over Q
__global__ void k_u(const float* __restrict__ umax, const float* __restrict__ umin,
                    const float* __restrict__ usum_b, const float* __restrict__ usumsq_b,
                    const float* __restrict__ g3, const float* __restrict__ be3,
                    float* __restrict__ u) {
    int tg = blockIdx.x * 256 + threadIdx.x;       // 0..4095 : (b,p)
    int b = tg >> 10, p = tg & 1023;
    float ub[16]; float sn = 0.f;
#pragma unroll
    for (int q = 0; q < 16; ++q) {
        int qp = q * 1024 + p;
        float s  = usum_b[qp] + usum_b[16384+qp] + usum_b[32768+qp] + usum_b[49152+qp];
        float ss = usumsq_b[qp] + usumsq_b[16384+qp] + usumsq_b[32768+qp] + usumsq_b[49152+qp];
        float mean  = s * (1.f/8192.f);
        float var   = ss * (1.f/8192.f) - mean*mean;
        float scale = g3[qp] * rsqrtf(var + BN_EPS);
        float val = (scale >= 0.f) ? umax[b*16384 + qp] : umin[b*16384 + qp];   // bn monotone in sign(scale)
        float vb = (val - mean) * scale + be3[qp];
        ub[q] = vb; sn = fmaf(vb, vb, sn);
    }
    float f = sqrtf(sn) / (1.f + sn);              // squash factor
#pragma unroll
    for (int q = 0; q < 16; ++q) u[tg*16 + q] = ub[q] * f;
}

// ---------------------------------------------------------------- u_hat in [b][p][l][v] layout + fused p-partial sums.
// uhat2[((b*1024+p)*64+l)*64+v] = sum_q Wr[l][p][v][q] u[b][p][q]
// s1p[((pblk*4+b)*64+l)*64+v] = sum over this block's 32 p.
__global__ __launch_bounds__(256) void k_uhat(const float* __restrict__ Wr,
                                              const float* __restrict__ u,
                                              float* __restrict__ uhat2,
                                              float* __restrict__ s1p) {
    const int t = threadIdx.x;
    const int pblk = blockIdx.x, l = blockIdx.y;
    __shared__ float wr[4][16][68];                // [p][q][v] padded
    __shared__ float us[4][4][16];                 // [p][b][q]
    const int bb = t >> 6, v = t & 63;
    float s1acc = 0.f;
    for (int sub = 0; sub < 8; ++sub) {
        const int p0 = pblk * 32 + sub * 4;
        const float* src = Wr + ((size_t)l * 1024 + p0) * 1024;
        if (sub) __syncthreads();                  // LDS reuse guard
#pragma unroll
        for (int it = 0; it < 4; ++it) {
            float4 d = *(const float4*)(src + (it*256 + t) * 4);
            int vv = t >> 2, q0 = (t & 3) * 4;     // p = it (wave-uniform)
            wr[it][q0  ][vv] = d.x; wr[it][q0+1][vv] = d.y;
            wr[it][q0+2][vv] = d.z; wr[it][q0+3][vv] = d.w;
        }
        {
            int p = t >> 6, b2 = (t >> 4) & 3, q = t & 15;
            us[p][b2][q] = u[((size_t)b2 * 1024 + p0 + p) * 16 + q];
        }
        __syncthreads();
#pragma unroll
        for (int p = 0; p < 4; ++p) {
            float acc = 0.f;
#pragma unroll
            for (int q = 0; q < 16; ++q) acc = fmaf(wr[p][q][v], us[p][bb][q], acc);
            uhat2[(((size_t)bb * 1024 + p0 + p) * 64 + l) * 64 + v] = acc;
            s1acc += acc;
        }
    }
    s1p[(((size_t)pblk * 4 + bb) * 64 + l) * 64 + v] = s1acc;
}

// ---------------------------------------------------------------- reduce s1 partials + squash -> v1
__global__ void k_s1red(const float* __restrict__ s1p, float* __restrict__ vout) {
    const int wv = blockIdx.x;                      // b*64 + l
    const int b = wv >> 6, l = wv & 63;
    const int v = threadIdx.x;
    float acc = 0.f;
#pragma unroll
    for (int pblk = 0; pblk < 32; ++pblk)
        acc += s1p[(((size_t)pblk * 4 + b) * 64 + l) * 64 + v];
    float s = acc * (1.f/64.f);
    float sn = s * s;
#pragma unroll
    for (int off = 32; off >= 1; off >>= 1) sn += __shfl_xor(sn, off);
    vout[wv * 64 + v] = s * sqrtf(sn) / (1.f + sn);
}

// ---------------------------------------------------------------- routing pass (B or C), uhat2 layout:
// per p: b_new[l] = (read_b ? bij : 0) + v_in[b][l][:].uhat2[b][p][l][:] ; c = softmax_l;
// s += c[l]*uhat2. Grid: 4 b x 128 chunks of 8 p. Partials reduced later.
__global__ __launch_bounds__(256) void k_route(const float* __restrict__ uhat2,
                                               const float* __restrict__ vin,
                                               float* __restrict__ bij,
                                               float* __restrict__ part, const int read_b) {
    const int blk = blockIdx.x;
    const int b = blk >> 7, ch = blk & 127;
    const int p0 = ch * 8;
    const int t = threadIdx.x;
    const int v = t & 63, w = t >> 6;
    __shared__ float uh[64][68];
    __shared__ float vs[64][68];
    __shared__ float bl[64];
    __shared__ float cl[64];
    {
        const float* src = vin + b * 4096;
        for (int i = t; i < 1024; i += 256) {
            float4 d = *(const float4*)(src + i * 4);
            int l = i >> 4, v0 = (i & 15) * 4;
            vs[l][v0] = d.x; vs[l][v0+1] = d.y; vs[l][v0+2] = d.z; vs[l][v0+3] = d.w;
        }
    }
    float sacc[16];
#pragma unroll
    for (int j = 0; j < 16; ++j) sacc[j] = 0.f;

    for (int pp = 0; pp < 8; ++pp) {
        const int p = p0 + pp;
        __syncthreads();
        const float* src = uhat2 + ((size_t)b * 1024 + p) * 4096;   // contiguous 16 KB
        for (int i = t; i < 1024; i += 256) {
            float4 d = *(const float4*)(src + i * 4);
            int l = i >> 4, v0 = (i & 15) * 4;
            uh[l][v0] = d.x; uh[l][v0+1] = d.y; uh[l][v0+2] = d.z; uh[l][v0+3] = d.w;
        }
        __syncthreads();
#pragma unroll
        for (int i = 0; i < 16; ++i) {
            const int l = w * 16 + i;
            float prod = uh[l][v] * vs[l][v];
#pragma unroll
            for (int off = 32; off >= 1; off >>= 1) prod += __shfl_xor(prod, off);
            if (v == 0) {
                float bb = prod;
                if (read_b) bb += bij[(b * 64 + l) * 1024 + p];
                bl[l] = bb;
                if (!read_b) bij[(b * 64 + l) * 1024 + p] = bb;
            }
        }
        __syncthreads();
        if (w == 0) {                               // softmax over l (lane = l)
            float xv = bl[v];
            float m = xv;
#pragma unroll
            for (int off = 32; off >= 1; off >>= 1) m = fmaxf(m, __shfl_xor(m, off));
            float e = expf(xv - m);
            float sgm = e;
#pragma unroll
            for (int off = 32; off >= 1; off >>= 1) sgm += __shfl_xor(sgm, off);
            cl[v] = e / sgm;
        }
        __syncthreads();
#pragma unroll
        for (int j = 0; j < 16; ++j) {
            const int l = j * 4 + w;
            sacc[j] = fmaf(cl[l], uh[l][v], sacc[j]);
        }
    }
#pragma unroll
    for (int j = 0; j < 16; ++j) {
        const int l = j * 4 + w;
        part[((size_t)(b * 128 + ch) * 64 + l) * 64 + v] = sacc[j];
    }
}

// ---------------------------------------------------------------- reduce partials + squash (+ presence)
__global__ void k_red_squash(const float* __restrict__ part, float* __restrict__ vout,
                             float* __restrict__ pres) {
    const int wv = blockIdx.x;                      // b*64 + l
    const int b = wv >> 6, l = wv & 63;
    const int v = threadIdx.x;
    float acc = 0.f;
    for (int ch = 0; ch < 128; ++ch) acc += part[((size_t)(b * 128 + ch) * 64 + l) * 64 + v];
    float sn = acc * acc;
#pragma unroll
    for (int off = 32; off >= 1; off >>= 1) sn += __shfl_xor(sn, off);
    vout[wv * 64 + v] = acc * sqrtf(sn) / (1.f + sn);
    if (pres != nullptr && v == 0) pres[wv] = sn / (1.f + sn);   // ||squash(s)|| = sn/(1+sn)
}

// ---------------------------------------------------------------- classifier head
__global__ void k_logits(const float* __restrict__ vj, const float* __restrict__ fcw,
                         const float* __restrict__ fcb, float* __restrict__ out) {
    int wv = blockIdx.x * 4 + (threadIdx.x >> 6);   // 0..159
    int lane = threadIdx.x & 63;
    int b = wv / 40, o = wv % 40;
    const float* xv = vj + b * 4096;
    const float* wr = fcw + (size_t)o * 4096;
    float acc = 0.f;
    for (int i = lane; i < 4096; i += 64) acc = fmaf(xv[i], wr[i], acc);
#pragma unroll
    for (int off = 32; off >= 1; off >>= 1) acc += __shfl_xor(acc, off);
    if (lane == 0) out[b * 40 + o] = acc + fcb[o];
}

extern "C" void kernel_launch(void* const* d_in, const int* in_sizes, int n_in,
                              void* d_out, int out_size, void* d_ws, size_t ws_size,
                              hipStream_t stream) {
    const float* x   = (const float*)d_in[0];
    const float* w1  = (const float*)d_in[1];
    // d_in[2] = b1: cancels under batch-norm
    const float* g1  = (const float*)d_in[3];
    const float* be1 = (const float*)d_in[4];
    const float* w2  = (const float*)d_in[5];
    // d_in[6] = b2: cancels
    const float* g2  = (const float*)d_in[7];
    const float* be2 = (const float*)d_in[8];
    const float* w3  = (const float*)d_in[9];
    // d_in[10] = b3: cancels
    const float* g3  = (const float*)d_in[11];
    const float* be3 = (const float*)d_in[12];
    const float* Wr  = (const float*)d_in[13];
    const float* fcw = (const float*)d_in[14];
    const float* fcb = (const float*)d_in[15];
    float* out = (float*)d_out;

    float* ws       = (float*)d_ws;
    float* y1       = ws;                   // [64][8192]
    float* y2       = y1 + 524288;          // [128][8192]
    float* mean1    = y2 + 1048576;         // 64
    float* inv1     = mean1 + 64;           // 64
    float* mean2    = inv1 + 64;            // 128
    float* inv2     = mean2 + 128;          // 128
    float* umax     = inv2 + 128;           // [4][16384]
    float* umin     = umax + 65536;         // [4][16384]
    float* usum_b   = umin + 65536;         // [4][16384] per-b partials
    float* usumsq_b = usum_b + 65536;       // [4][16384]
    float* u        = usumsq_b + 65536;     // [4][1024][16]
    float* v1       = u + 65536;            // [4][64][64]
    float* v2       = v1 + 16384;
    float* vj       = v2 + 16384;
    float* bij      = vj + 16384;           // [4][64][1024]
    float* s1p      = bij + 262144;         // [32][4][64][64] (2 MB)
    float* part     = s1p + 524288;         // [4][128][64][64] (8 MB)
    float* uhat2    = part + 2097152;       // [4][1024][64][64]  (64 MB), [b][p][l][v]
    // fp16 staging buffers alias the uhat2 region: dead before k_uhat writes it.
    _Float16* w3h = (_Float16*)uhat2;       // [16384][128]
    _Float16* w3l = w3h + 2097152;
    _Float16* h2h = w3l + 2097152;          // [8192][128] (bn-major)
    _Float16* h2l = h2h + 1048576;

    k_conv1stats<<<64, 256, 0, stream>>>(x, w1, y1, mean1, inv1);
    k_conv2<<<dim3(8, 32), 256, 0, stream>>>(y1, w2, mean1, inv1, g1, be1, y2);
    k_stats<<<128, 256, 0, stream>>>(y2, mean2, inv2);
    k_split_w3<<<512, 256, 0, stream>>>(w3, w3h, w3l);
    k_h2t_split<<<dim3(128, 2), 256, 0, stream>>>(y2, mean2, inv2, g2, be2, h2h, h2l);
    k_caps<<<dim3(128, 4), 256, 0, stream>>>(w3h, w3l, h2h, h2l, umax, umin, usum_b, usumsq_b);
    k_u<<<16, 256, 0, stream>>>(umax, umin, usum_b, usumsq_b, g3, be3, u);
    k_uhat<<<dim3(32, 64), 256, 0, stream>>>(Wr, u, uhat2, s1p);
    k_s1red<<<256, 64, 0, stream>>>(s1p, v1);
    k_route<<<512, 256, 0, stream>>>(uhat2, v1, bij, part, 0);
    k_red_squash<<<256, 64, 0, stream>>>(part, v2, nullptr);
    k_route<<<512, 256, 0, stream>>>(uhat2, v2, bij, part, 1);
    k_red_squash<<<256, 64, 0, stream>>>(part, vj, out + 160);
    k_logits<<<40, 256, 0, stream>>>(vj, fcw, fcb, out);
}